// Round 7
// baseline (594.430 us; speedup 1.0000x reference)
//
#include <hip/hip_runtime.h>
#include <hip/hip_bf16.h>

#define E_     8
#define C_     1024
#define H_     4096
#define N_TOK  4096
#define TOPK   2
#define NSLOT  (N_TOK*TOPK)   // 8192
#define SPAD   (NSLOT+256)    // padded rows for 256-row tile-tail reads

#define LPAD 40               // slow-path LDS row stride

typedef __attribute__((ext_vector_type(4))) float f32x4;
typedef __attribute__((ext_vector_type(8))) short short8;

__device__ __forceinline__ unsigned short f2bf(float f) {
    return __builtin_bit_cast(unsigned short, __float2bfloat16(f));
}

__device__ __forceinline__ void gload16(const void* g, const void* l) {
    __builtin_amdgcn_global_load_lds(
        (const __attribute__((address_space(1))) unsigned int*)g,
        (__attribute__((address_space(3))) unsigned int*)l, 16, 0, 0);
}

#define WAITVM_(n) asm volatile("s_waitcnt vmcnt(" #n ")" ::: "memory")
#define WAITVM(n) WAITVM_(n)

// ---------------- router: 1 wave per token (no atomics) ----------------
__global__ void router_kernel(const float* __restrict__ x, const float* __restrict__ Wg,
                              int* __restrict__ sel, float* __restrict__ wts) {
    int wave = (blockIdx.x * blockDim.x + threadIdx.x) >> 6;
    int lane = threadIdx.x & 63;
    if (wave >= N_TOK) return;
    const float* xr = x + (size_t)wave * C_;
    float acc[E_];
#pragma unroll
    for (int e = 0; e < E_; ++e) acc[e] = 0.f;
    for (int c = lane; c < C_; c += 64) {
        float xv = xr[c];
#pragma unroll
        for (int e = 0; e < E_; ++e) acc[e] += xv * Wg[e * C_ + c];
    }
#pragma unroll
    for (int e = 0; e < E_; ++e) {
#pragma unroll
        for (int off = 32; off > 0; off >>= 1) acc[e] += __shfl_xor(acc[e], off);
    }
    if (lane == 0) {
        float mx = acc[0];
#pragma unroll
        for (int e = 1; e < E_; ++e) mx = fmaxf(mx, acc[e]);
        float p[E_]; float s = 0.f;
#pragma unroll
        for (int e = 0; e < E_; ++e) { p[e] = __expf(acc[e] - mx); s += p[e]; }
        float inv = 1.f / s;
#pragma unroll
        for (int e = 0; e < E_; ++e) p[e] *= inv;
        int b0 = 0; float v0 = p[0];
#pragma unroll
        for (int e = 1; e < E_; ++e) if (p[e] > v0) { v0 = p[e]; b0 = e; }
        int b1 = -1; float v1 = -1.f;
#pragma unroll
        for (int e = 0; e < E_; ++e) { if (e != b0 && p[e] > v1) { v1 = p[e]; b1 = e; } }
        float isum = 1.f / (v0 + v1);
        sel[wave*2]   = b0; sel[wave*2+1] = b1;
        wts[wave*2]   = v0 * isum; wts[wave*2+1] = v1 * isum;
    }
}

// ---------------- assign: deterministic positions, single block ----------------
__global__ void assign_kernel(const int* __restrict__ sel, const float* __restrict__ wts,
                              int* __restrict__ counts, int* __restrict__ offsets,
                              int* __restrict__ pos_of_slot, int* __restrict__ token_of,
                              float* __restrict__ slotw) {
    __shared__ int cnt[256][E_];
    __shared__ int offs[E_];
    int t = threadIdx.x;
    const int PER = NSLOT / 256;   // 32
    int base = t * PER;
    int loc[E_];
#pragma unroll
    for (int e = 0; e < E_; ++e) loc[e] = 0;
    for (int i = 0; i < PER; ++i) loc[sel[base + i]]++;
#pragma unroll
    for (int e = 0; e < E_; ++e) cnt[t][e] = loc[e];
    __syncthreads();
    if (t < E_) {
        int run = 0;
        for (int i = 0; i < 256; ++i) { int c = cnt[i][t]; cnt[i][t] = run; run += c; }
        counts[t] = run;
    }
    __syncthreads();
    if (t == 0) {
        int s = 0;
        for (int e = 0; e < E_; ++e) { offs[e] = s; offsets[e] = s; s += counts[e]; }
    }
    __syncthreads();
    int run[E_];
#pragma unroll
    for (int e = 0; e < E_; ++e) run[e] = offs[e] + cnt[t][e];
    for (int i = 0; i < PER; ++i) {
        int s = base + i;
        int e = sel[s];
        int p = run[e]++;
        pos_of_slot[s] = p;
        token_of[p] = s >> 1;
        slotw[p] = wts[s];
    }
}

// ---------------- copy: gather token rows to bf16 ----------------
__global__ void copy_kernel(const float* __restrict__ x, const int* __restrict__ pos_of_slot,
                            unsigned short* __restrict__ Xg) {
    int slot = blockIdx.x * 4 + (threadIdx.x >> 6);
    int lane = threadIdx.x & 63;
    int pos = pos_of_slot[slot];
    int n = slot >> 1;
    const float* xr = x + (size_t)n * C_;
    unsigned short* dst = Xg + (size_t)pos * C_;
#pragma unroll
    for (int i = 0; i < 4; ++i) {
        int c0 = i * 256 + lane * 4;
        float4 v = *(const float4*)(xr + c0);
        ushort4 b;
        b.x = f2bf(v.x); b.y = f2bf(v.y); b.z = f2bf(v.z); b.w = f2bf(v.w);
        *(ushort4*)(dst + c0) = b;
    }
}

// ---------------- wconv: per-expert transpose fp32 [R][Cc] -> bf16 [Cc][R] ----------------
__global__ void wconv_kernel(const float* __restrict__ src, unsigned short* __restrict__ dst,
                             int R, int Cc) {
    int e = blockIdx.z;
    int c0 = blockIdx.x * 64;
    int r0 = blockIdx.y * 64;
    const float* s = src + (size_t)e * R * Cc;
    unsigned short* d = dst + (size_t)e * R * Cc;
    __shared__ unsigned short t_[64][72];
    int t = threadIdx.x;
    int tr = t >> 4, tc4 = (t & 15) * 4;
#pragma unroll
    for (int i = 0; i < 4; ++i) {
        int r = tr + i * 16;
        float4 v = *(const float4*)(s + (size_t)(r0 + r) * Cc + c0 + tc4);
        t_[r][tc4+0] = f2bf(v.x); t_[r][tc4+1] = f2bf(v.y);
        t_[r][tc4+2] = f2bf(v.z); t_[r][tc4+3] = f2bf(v.w);
    }
    __syncthreads();
    int oc = t >> 2, seg = (t & 3) * 16;
    short8 w0, w1;
#pragma unroll
    for (int j = 0; j < 8; ++j) {
        w0[j] = (short)t_[seg + j][oc];
        w1[j] = (short)t_[seg + 8 + j][oc];
    }
    unsigned short* dp = d + (size_t)(c0 + oc) * R + r0 + seg;
    *(short8*)dp = w0;
    *(short8*)(dp + 8) = w1;
}

// ============ ring GEMMs v3: 256x128 tile, transposed-block LDS, 8 waves ============
// LDS layout: 1024B blocks, block g = rows [g*16,g*16+16) x 4 chunks(16B), chunk-major.
// Staged per-lane (row=lane&15, chunk=lane>>4), LDS dest linear -> conflict-free reads.
// XCD swizzle (bijective): b=by*gdx+bx; e=b&7; j=b>>3; ct=j%nct; rt=j/nct.
//   -> XCD x runs only expert x: A-panels L2-resident across its ct-blocks; each XCD
//   touches only its own expert's weights (W fetched from HBM once, L3 thereafter).
// gemm1: 4-slot ring, 2 sub-phases (acc1 then acc3, a-frags reused in regs).
// gemm2: 6-slot ring (LDS 144KB), stage-lead 5 halves, WAITVM(12).

#define G1_NH (C_/32)    // 32 K-halves

__global__ __launch_bounds__(512, 2) void gemm1_ring(
        const unsigned short* __restrict__ Xg, const unsigned short* __restrict__ W1t,
        const unsigned short* __restrict__ W3t, unsigned short* __restrict__ G,
        const int* __restrict__ counts, const int* __restrict__ offsets) {
    int b = blockIdx.y * 32 + blockIdx.x;   // [0, 8192)
    int e = b & 7;
    int j = b >> 3;                         // [0, 1024)
    int ct = j & 31;                        // 32 col tiles
    int rt = j >> 5;                        // [0, 32)
    int ne = counts[e];
    if (rt * 256 >= ne) return;
    int row0 = offsets[e] + rt * 256;
    int n0 = ct * 128;

    extern __shared__ char lds[];
    char* As  = lds;            // 4 slots x 16384 B (16 blocks of 1024B)
    char* B1s = lds + 65536;    // 4 slots x 8192 B  (8 blocks)
    char* B3s = lds + 98304;    // 4 slots x 8192 B

    int tid = threadIdx.x, lane = tid & 63, wid = tid >> 6;
    int wm = wid >> 1, wn = wid & 1;
    int fr = lane & 15, q = lane >> 4;
    int arow = lane & 15, akch = lane >> 4;   // staging lane map

    const unsigned short* Ap  = Xg + (size_t)row0 * C_;
    const unsigned short* B1p = W1t + ((size_t)e * H_ + n0) * C_;
    const unsigned short* B3p = W3t + ((size_t)e * H_ + n0) * C_;

    f32x4 acc1[4][4], acc3[4][4];
#pragma unroll
    for (int m = 0; m < 4; ++m)
#pragma unroll
        for (int n = 0; n < 4; ++n) {
            acc1[m][n] = (f32x4){0.f,0.f,0.f,0.f};
            acc3[m][n] = (f32x4){0.f,0.f,0.f,0.f};
        }

    auto STAGE_A = [&](int hs, int slot) {
        int k0 = hs * 32;
#pragma unroll
        for (int jj = 0; jj < 2; ++jj) {
            int g = wid + jj * 8;    // block index 0..15
            gload16(Ap + (size_t)(g * 16 + arow) * C_ + k0 + akch * 8,
                    As + slot * 16384 + g * 1024);
        }
    };
    auto STAGE_B = [&](int hs, int slot) {
        int k0 = hs * 32;
        gload16(B1p + (size_t)(wid * 16 + arow) * C_ + k0 + akch * 8,
                B1s + slot * 8192 + wid * 1024);
        gload16(B3p + (size_t)(wid * 16 + arow) * C_ + k0 + akch * 8,
                B3s + slot * 8192 + wid * 1024);
    };

    // prologue: stage halves 0,1,2 -> 12 loads in flight
    STAGE_A(0, 0); STAGE_B(0, 0);
    STAGE_A(1, 1); STAGE_B(1, 1);
    STAGE_A(2, 2); STAGE_B(2, 2);
    WAITVM(8);                      // half 0 landed
    __builtin_amdgcn_s_barrier();

    for (int h = 0; h < G1_NH; ++h) {
        int slot = h & 3;
        int hs = (h + 3 < G1_NH) ? h + 3 : G1_NH - 1;   // tail: dummy re-stage (ledger invariant)
        int wslot = (h + 3) & 3;
        short8 a[4], b1[4], b3[4];
        // ---- phase A: read a,b1(slot h); stage A-part(h+3); MFMA acc1 ----
#pragma unroll
        for (int m = 0; m < 4; ++m)
            a[m] = *(const short8*)(As + slot * 16384 + (wm * 4 + m) * 1024 + q * 256 + fr * 16);
#pragma unroll
        for (int n = 0; n < 4; ++n)
            b1[n] = *(const short8*)(B1s + slot * 8192 + (wn * 4 + n) * 1024 + q * 256 + fr * 16);
        STAGE_A(hs, wslot);
        __builtin_amdgcn_sched_barrier(0);
        __builtin_amdgcn_s_barrier();
        __builtin_amdgcn_s_setprio(1);
#pragma unroll
        for (int m = 0; m < 4; ++m)
#pragma unroll
            for (int n = 0; n < 4; ++n)
                acc1[m][n] = __builtin_amdgcn_mfma_f32_16x16x32_bf16(a[m], b1[n], acc1[m][n], 0, 0, 0);
        __builtin_amdgcn_s_setprio(0);
        __builtin_amdgcn_s_barrier();
        // ---- phase B: read b3(slot h); stage B-part(h+3); retire half h+1; MFMA acc3 ----
#pragma unroll
        for (int n = 0; n < 4; ++n)
            b3[n] = *(const short8*)(B3s + slot * 8192 + (wn * 4 + n) * 1024 + q * 256 + fr * 16);
        STAGE_B(hs, wslot);
        WAITVM(8);
        __builtin_amdgcn_sched_barrier(0);
        __builtin_amdgcn_s_barrier();
        __builtin_amdgcn_s_setprio(1);
#pragma unroll
        for (int m = 0; m < 4; ++m)
#pragma unroll
            for (int n = 0; n < 4; ++n)
                acc3[m][n] = __builtin_amdgcn_mfma_f32_16x16x32_bf16(a[m], b3[n], acc3[m][n], 0, 0, 0);
        __builtin_amdgcn_s_setprio(0);
        __builtin_amdgcn_s_barrier();
    }
    WAITVM(0);   // drain dummy staging before kernel end

    // epilogue: silu(h1)*h3 -> bf16 G
#pragma unroll
    for (int m = 0; m < 4; ++m)
#pragma unroll
        for (int rg = 0; rg < 4; ++rg) {
            int row = wm*64 + m*16 + q*4 + rg;
            if (rt * 256 + row < ne) {
                size_t gbase = (size_t)(row0 + row) * H_ + n0 + wn*64;
#pragma unroll
                for (int n = 0; n < 4; ++n) {
                    float h1 = acc1[m][n][rg];
                    float h3 = acc3[m][n][rg];
                    float g = h1 * h3 / (1.f + __expf(-h1));
                    G[gbase + n*16 + fr] = f2bf(g);
                }
            }
        }
}

#define G2_NH (H_/32)    // 128 K-halves

__global__ __launch_bounds__(512, 2) void gemm2_ring(
        const unsigned short* __restrict__ G, const unsigned short* __restrict__ W2t,
        float* __restrict__ out, const int* __restrict__ counts,
        const int* __restrict__ offsets, const int* __restrict__ token_of,
        const float* __restrict__ slotw) {
    int b = blockIdx.y * 8 + blockIdx.x;    // [0, 2048)
    int e = b & 7;
    int j = b >> 3;                         // [0, 256)
    int ct = j & 7;                         // 8 col tiles
    int rt = j >> 3;                        // [0, 32)
    int ne = counts[e];
    if (rt * 256 >= ne) return;
    int row0 = offsets[e] + rt * 256;
    int n0 = ct * 128;

    extern __shared__ char lds[];
    char* As = lds;             // 6 slots x 16384 B
    char* Bs = lds + 98304;     // 6 slots x 8192 B   (total 144KB)

    int tid = threadIdx.x, lane = tid & 63, wid = tid >> 6;
    int wm = wid >> 1, wn = wid & 1;
    int fr = lane & 15, q = lane >> 4;
    int arow = lane & 15, akch = lane >> 4;

    const unsigned short* Ap = G + (size_t)row0 * H_;
    const unsigned short* Bp = W2t + ((size_t)e * C_ + n0) * H_;

    f32x4 acc[4][4];
#pragma unroll
    for (int m = 0; m < 4; ++m)
#pragma unroll
        for (int n = 0; n < 4; ++n) acc[m][n] = (f32x4){0.f,0.f,0.f,0.f};

    auto STAGE = [&](int hs, int slot) {
        int k0 = hs * 32;
#pragma unroll
        for (int jj = 0; jj < 2; ++jj) {
            int g = wid + jj * 8;
            gload16(Ap + (size_t)(g * 16 + arow) * H_ + k0 + akch * 8,
                    As + slot * 16384 + g * 1024);
        }
        gload16(Bp + (size_t)(wid * 16 + arow) * H_ + k0 + akch * 8,
                Bs + slot * 8192 + wid * 1024);
    };

    // prologue: stage halves 0..4 -> 15 loads in flight
    STAGE(0, 0); STAGE(1, 1); STAGE(2, 2); STAGE(3, 3); STAGE(4, 4);
    WAITVM(12);                              // half 0 landed
    __builtin_amdgcn_s_barrier();

    int slot = 0, wslot = 5;
    for (int h = 0; h < G2_NH; ++h) {
        int hs = (h + 5 < G2_NH) ? h + 5 : G2_NH - 1;   // tail: dummy re-stage
        short8 a[4], bfr[4];
#pragma unroll
        for (int m = 0; m < 4; ++m)
            a[m] = *(const short8*)(As + slot * 16384 + (wm * 4 + m) * 1024 + q * 256 + fr * 16);
#pragma unroll
        for (int n = 0; n < 4; ++n)
            bfr[n] = *(const short8*)(Bs + slot * 8192 + (wn * 4 + n) * 1024 + q * 256 + fr * 16);
        STAGE(hs, wslot);
        WAITVM(12);                          // retires half h+1
        __builtin_amdgcn_sched_barrier(0);
        __builtin_amdgcn_s_barrier();
        __builtin_amdgcn_s_setprio(1);
#pragma unroll
        for (int m = 0; m < 4; ++m)
#pragma unroll
            for (int n = 0; n < 4; ++n)
                acc[m][n] = __builtin_amdgcn_mfma_f32_16x16x32_bf16(a[m], bfr[n], acc[m][n], 0, 0, 0);
        __builtin_amdgcn_s_setprio(0);
        __builtin_amdgcn_s_barrier();
        slot = (slot == 5) ? 0 : slot + 1;
        wslot = (wslot == 5) ? 0 : wslot + 1;
    }
    WAITVM(0);

    // epilogue: scatter-add weighted partial into out
#pragma unroll
    for (int m = 0; m < 4; ++m)
#pragma unroll
        for (int rg = 0; rg < 4; ++rg) {
            int row = wm*64 + m*16 + q*4 + rg;
            if (rt * 256 + row < ne) {
                int grow = row0 + row;
                int tok = token_of[grow];
                float w = slotw[grow];
                float* orow = out + (size_t)tok * C_ + n0 + wn*64;
#pragma unroll
                for (int n = 0; n < 4; ++n)
                    atomicAdd(orow + n*16 + fr, acc[m][n][rg] * w);
            }
        }
}

// ============ SLOW PATH (fallback if ws too small) ============
#define BM 128
#define BN 128
#define BK 32
__global__ __launch_bounds__(256, 2) void gemm1_slow(
        const unsigned short* __restrict__ Xg, const float* __restrict__ W1,
        const float* __restrict__ W3, unsigned short* __restrict__ G,
        const int* __restrict__ counts, const int* __restrict__ offsets) {
    int ct = blockIdx.x;
    int rslot = blockIdx.y;
    int e = rslot >> 5, rt = rslot & 31;
    int ne = counts[e];
    if (rt * BM >= ne) return;
    int row0 = offsets[e] + rt * BM;
    int n0 = ct * BN;

    __shared__ unsigned short As[BM][LPAD];
    __shared__ unsigned short B1s[BN][LPAD];
    __shared__ unsigned short B3s[BN][LPAD];

    int tid = threadIdx.x;
    int lane = tid & 63, wid = tid >> 6;
    int wr = (wid >> 1) * 64, wc = (wid & 1) * 64;

    f32x4 acc1[4][4], acc3[4][4];
#pragma unroll
    for (int m = 0; m < 4; ++m)
#pragma unroll
        for (int n = 0; n < 4; ++n) {
            acc1[m][n] = (f32x4){0.f,0.f,0.f,0.f};
            acc3[m][n] = (f32x4){0.f,0.f,0.f,0.f};
        }

    const float* B1p = W1 + (size_t)e * C_ * H_ + n0;
    const float* B3p = W3 + (size_t)e * C_ * H_ + n0;
    int chunk = tid & 3, rr = tid >> 2;
    int kq = tid >> 5, n4 = tid & 31;

    for (int k0 = 0; k0 < C_; k0 += BK) {
        __syncthreads();
#pragma unroll
        for (int h = 0; h < 2; ++h) {
            int row = rr + h * 64;
            uint4 v = *(const uint4*)(Xg + (size_t)(row0 + row) * C_ + k0 + chunk * 8);
            *(uint4*)&As[row][chunk * 8] = v;
        }
        {
            float4 r0 = *(const float4*)(B1p + (size_t)(k0 + kq*4 + 0) * H_ + n4*4);
            float4 r1 = *(const float4*)(B1p + (size_t)(k0 + kq*4 + 1) * H_ + n4*4);
            float4 r2 = *(const float4*)(B1p + (size_t)(k0 + kq*4 + 2) * H_ + n4*4);
            float4 r3 = *(const float4*)(B1p + (size_t)(k0 + kq*4 + 3) * H_ + n4*4);
            ushort4 w0 = {f2bf(r0.x), f2bf(r1.x), f2bf(r2.x), f2bf(r3.x)};
            ushort4 w1 = {f2bf(r0.y), f2bf(r1.y), f2bf(r2.y), f2bf(r3.y)};
            ushort4 w2 = {f2bf(r0.z), f2bf(r1.z), f2bf(r2.z), f2bf(r3.z)};
            ushort4 w3 = {f2bf(r0.w), f2bf(r1.w), f2bf(r2.w), f2bf(r3.w)};
            *(ushort4*)&B1s[n4*4+0][kq*4] = w0;
            *(ushort4*)&B1s[n4*4+1][kq*4] = w1;
            *(ushort4*)&B1s[n4*4+2][kq*4] = w2;
            *(ushort4*)&B1s[n4*4+3][kq*4] = w3;
            r0 = *(const float4*)(B3p + (size_t)(k0 + kq*4 + 0) * H_ + n4*4);
            r1 = *(const float4*)(B3p + (size_t)(k0 + kq*4 + 1) * H_ + n4*4);
            r2 = *(const float4*)(B3p + (size_t)(k0 + kq*4 + 2) * H_ + n4*4);
            r3 = *(const float4*)(B3p + (size_t)(k0 + kq*4 + 3) * H_ + n4*4);
            w0 = (ushort4){f2bf(r0.x), f2bf(r1.x), f2bf(r2.x), f2bf(r3.x)};
            w1 = (ushort4){f2bf(r0.y), f2bf(r1.y), f2bf(r2.y), f2bf(r3.y)};
            w2 = (ushort4){f2bf(r0.z), f2bf(r1.z), f2bf(r2.z), f2bf(r3.z)};
            w3 = (ushort4){f2bf(r0.w), f2bf(r1.w), f2bf(r2.w), f2bf(r3.w)};
            *(ushort4*)&B3s[n4*4+0][kq*4] = w0;
            *(ushort4*)&B3s[n4*4+1][kq*4] = w1;
            *(ushort4*)&B3s[n4*4+2][kq*4] = w2;
            *(ushort4*)&B3s[n4*4+3][kq*4] = w3;
        }
        __syncthreads();
        int q = lane >> 4, fr = lane & 15;
        short8 a[4], b1[4], b3[4];
#pragma unroll
        for (int m = 0; m < 4; ++m) a[m] = *(const short8*)&As[wr + m*16 + fr][q*8];
#pragma unroll
        for (int n = 0; n < 4; ++n) {
            b1[n] = *(const short8*)&B1s[wc + n*16 + fr][q*8];
            b3[n] = *(const short8*)&B3s[wc + n*16 + fr][q*8];
        }
#pragma unroll
        for (int m = 0; m < 4; ++m)
#pragma unroll
            for (int n = 0; n < 4; ++n) {
                acc1[m][n] = __builtin_amdgcn_mfma_f32_16x16x32_bf16(a[m], b1[n], acc1[m][n], 0, 0, 0);
                acc3[m][n] = __builtin_amdgcn_mfma_f32_16x16x32_bf16(a[m], b3[n], acc3[m][n], 0, 0, 0);
            }
    }
    int q = lane >> 4, cfr = lane & 15;
#pragma unroll
    for (int m = 0; m < 4; ++m) {
#pragma unroll
        for (int rg = 0; rg < 4; ++rg) {
            int row = wr + m*16 + q*4 + rg;
            if (rt * BM + row < ne) {
                size_t gbase = (size_t)(row0 + row) * H_ + n0;
#pragma unroll
                for (int n = 0; n < 4; ++n) {
                    float h1 = acc1[m][n][rg];
                    float h3 = acc3[m][n][rg];
                    float g = h1 * h3 / (1.f + __expf(-h1));
                    G[gbase + wc + n*16 + cfr] = f2bf(g);
                }
            }
        }
    }
}

__global__ __launch_bounds__(256, 2) void gemm2_slow(
        const unsigned short* __restrict__ G, const float* __restrict__ W2,
        float* __restrict__ out, const int* __restrict__ counts,
        const int* __restrict__ offsets, const int* __restrict__ token_of,
        const float* __restrict__ slotw) {
    int ct = blockIdx.x;
    int rslot = blockIdx.y;
    int e = rslot >> 5, rt = rslot & 31;
    int ne = counts[e];
    if (rt * BM >= ne) return;
    int row0 = offsets[e] + rt * BM;
    int n0 = ct * BN;

    __shared__ unsigned short As[BM][LPAD];
    __shared__ unsigned short Bs[BN][LPAD];

    int tid = threadIdx.x;
    int lane = tid & 63, wid = tid >> 6;
    int wr = (wid >> 1) * 64, wc = (wid & 1) * 64;

    f32x4 acc[4][4];
#pragma unroll
    for (int m = 0; m < 4; ++m)
#pragma unroll
        for (int n = 0; n < 4; ++n) acc[m][n] = (f32x4){0.f,0.f,0.f,0.f};

    const float* Bp = W2 + (size_t)e * H_ * C_ + n0;
    int chunk = tid & 3, rr = tid >> 2;
    int kq = tid >> 5, n4 = tid & 31;

    for (int k0 = 0; k0 < H_; k0 += BK) {
        __syncthreads();
#pragma unroll
        for (int h = 0; h < 2; ++h) {
            int row = rr + h * 64;
            uint4 v = *(const uint4*)(G + (size_t)(row0 + row) * H_ + k0 + chunk * 8);
            *(uint4*)&As[row][chunk * 8] = v;
        }
        {
            float4 r0 = *(const float4*)(Bp + (size_t)(k0 + kq*4 + 0) * C_ + n4*4);
            float4 r1 = *(const float4*)(Bp + (size_t)(k0 + kq*4 + 1) * C_ + n4*4);
            float4 r2 = *(const float4*)(Bp + (size_t)(k0 + kq*4 + 2) * C_ + n4*4);
            float4 r3 = *(const float4*)(Bp + (size_t)(k0 + kq*4 + 3) * C_ + n4*4);
            ushort4 w0 = {f2bf(r0.x), f2bf(r1.x), f2bf(r2.x), f2bf(r3.x)};
            ushort4 w1 = {f2bf(r0.y), f2bf(r1.y), f2bf(r2.y), f2bf(r3.y)};
            ushort4 w2 = {f2bf(r0.z), f2bf(r1.z), f2bf(r2.z), f2bf(r3.z)};
            ushort4 w3 = {f2bf(r0.w), f2bf(r1.w), f2bf(r2.w), f2bf(r3.w)};
            *(ushort4*)&Bs[n4*4+0][kq*4] = w0;
            *(ushort4*)&Bs[n4*4+1][kq*4] = w1;
            *(ushort4*)&Bs[n4*4+2][kq*4] = w2;
            *(ushort4*)&Bs[n4*4+3][kq*4] = w3;
        }
        __syncthreads();
        int q = lane >> 4, fr = lane & 15;
        short8 a[4], b[4];
#pragma unroll
        for (int m = 0; m < 4; ++m) a[m] = *(const short8*)&As[wr + m*16 + fr][q*8];
#pragma unroll
        for (int n = 0; n < 4; ++n) b[n] = *(const short8*)&Bs[wc + n*16 + fr][q*8];
#pragma unroll
        for (int m = 0; m < 4; ++m)
#pragma unroll
            for (int n = 0; n < 4; ++n)
                acc[m][n] = __builtin_amdgcn_mfma_f32_16x16x32_bf16(a[m], b[n], acc[m][n], 0, 0, 0);
    }
    int q = lane >> 4, cfr = lane & 15;
#pragma unroll
    for (int m = 0; m < 4; ++m) {
#pragma unroll
        for (int rg = 0; rg < 4; ++rg) {
            int row = wr + m*16 + q*4 + rg;
            if (rt * BM + row < ne) {
                int grow = row0 + row;
                int tok = token_of[grow];
                float w = slotw[grow];
                float* orow = out + (size_t)tok * C_ + n0;
#pragma unroll
                for (int n = 0; n < 4; ++n)
                    atomicAdd(orow + wc + n*16 + cfr, acc[m][n][rg] * w);
            }
        }
    }
}

extern "C" void kernel_launch(void* const* d_in, const int* in_sizes, int n_in,
                              void* d_out, int out_size, void* d_ws, size_t ws_size,
                              hipStream_t stream) {
    const float* x  = (const float*)d_in[0];
    const float* Wg = (const float*)d_in[1];
    const float* W1 = (const float*)d_in[2];
    const float* W2 = (const float*)d_in[3];
    const float* W3 = (const float*)d_in[4];
    float* out = (float*)d_out;

    char* ws = (char*)d_ws;
    size_t o = 0;
    int*   sel      = (int*)(ws + o);  o += (size_t)NSLOT * 4;
    float* wts      = (float*)(ws + o); o += (size_t)NSLOT * 4;
    int*   pos      = (int*)(ws + o);  o += (size_t)NSLOT * 4;
    int*   token_of = (int*)(ws + o);  o += (size_t)NSLOT * 4;
    float* slotw    = (float*)(ws + o); o += (size_t)NSLOT * 4;
    int*   counts   = (int*)(ws + o);
    int*   offsets  = counts + E_;     o += 256;
    unsigned short* Xg = (unsigned short*)(ws + o); o += (size_t)SPAD * C_ * 2;
    unsigned short* G  = (unsigned short*)(ws + o); o += (size_t)SPAD * H_ * 2;
    size_t need_slow = o;
    unsigned short* W1t = (unsigned short*)(ws + o); o += (size_t)E_ * H_ * C_ * 2;
    unsigned short* W3t = (unsigned short*)(ws + o); o += (size_t)E_ * H_ * C_ * 2;
    unsigned short* W2t = W1t;   // W1t region freed after gemm1
    size_t need_fast = o;

    hipMemsetAsync(d_out, 0, (size_t)out_size * sizeof(float), stream);
    if (ws_size < need_slow) return;

    router_kernel<<<N_TOK/4, 256, 0, stream>>>(x, Wg, sel, wts);
    assign_kernel<<<1, 256, 0, stream>>>(sel, wts, counts, offsets, pos, token_of, slotw);
    copy_kernel<<<NSLOT/4, 256, 0, stream>>>(x, pos, Xg);

    if (ws_size >= need_fast) {
        hipFuncSetAttribute((const void*)gemm1_ring, hipFuncAttributeMaxDynamicSharedMemorySize, 131072);
        hipFuncSetAttribute((const void*)gemm2_ring, hipFuncAttributeMaxDynamicSharedMemorySize, 147456);
        wconv_kernel<<<dim3(H_/64, C_/64, E_), 256, 0, stream>>>(W1, W1t, C_, H_);
        wconv_kernel<<<dim3(H_/64, C_/64, E_), 256, 0, stream>>>(W3, W3t, C_, H_);
        gemm1_ring<<<dim3(H_/128, E_*32), 512, 131072, stream>>>(Xg, W1t, W3t, G, counts, offsets);
        wconv_kernel<<<dim3(C_/64, H_/64, E_), 256, 0, stream>>>(W2, W2t, H_, C_);
        gemm2_ring<<<dim3(C_/128, E_*32), 512, 147456, stream>>>(G, W2t, out, counts, offsets, token_of, slotw);
    } else {
        gemm1_slow<<<dim3(H_/BN, E_*32), 256, 0, stream>>>(Xg, W1, W3, G, counts, offsets);
        gemm2_slow<<<dim3(C_/BN, E_*32), 256, 0, stream>>>(G, W2, out, counts, offsets, token_of, slotw);
    }
}

// Round 8
// 589.900 us; speedup vs baseline: 1.0077x; 1.0077x over previous
//
#include <hip/hip_runtime.h>
#include <hip/hip_bf16.h>

#define E_     8
#define C_     1024
#define H_     4096
#define N_TOK  4096
#define TOPK   2
#define NSLOT  (N_TOK*TOPK)   // 8192
#define SPAD   (NSLOT+256)    // padded rows for tile-tail reads

#define LPAD 40               // slow-path LDS row stride

typedef __attribute__((ext_vector_type(4))) float f32x4;
typedef __attribute__((ext_vector_type(8))) short short8;

__device__ __forceinline__ unsigned short f2bf(float f) {
    return __builtin_bit_cast(unsigned short, __float2bfloat16(f));
}

__device__ __forceinline__ void gload16(const void* g, const void* l) {
    __builtin_amdgcn_global_load_lds(
        (const __attribute__((address_space(1))) unsigned int*)g,
        (__attribute__((address_space(3))) unsigned int*)l, 16, 0, 0);
}

#define WAITVM_(n) asm volatile("s_waitcnt vmcnt(" #n ")" ::: "memory")
#define WAITVM(n) WAITVM_(n)

// ---------------- router: 1 wave per token (no atomics) ----------------
__global__ void router_kernel(const float* __restrict__ x, const float* __restrict__ Wg,
                              int* __restrict__ sel, float* __restrict__ wts) {
    int wave = (blockIdx.x * blockDim.x + threadIdx.x) >> 6;
    int lane = threadIdx.x & 63;
    if (wave >= N_TOK) return;
    const float* xr = x + (size_t)wave * C_;
    float acc[E_];
#pragma unroll
    for (int e = 0; e < E_; ++e) acc[e] = 0.f;
    for (int c = lane; c < C_; c += 64) {
        float xv = xr[c];
#pragma unroll
        for (int e = 0; e < E_; ++e) acc[e] += xv * Wg[e * C_ + c];
    }
#pragma unroll
    for (int e = 0; e < E_; ++e) {
#pragma unroll
        for (int off = 32; off > 0; off >>= 1) acc[e] += __shfl_xor(acc[e], off);
    }
    if (lane == 0) {
        float mx = acc[0];
#pragma unroll
        for (int e = 1; e < E_; ++e) mx = fmaxf(mx, acc[e]);
        float p[E_]; float s = 0.f;
#pragma unroll
        for (int e = 0; e < E_; ++e) { p[e] = __expf(acc[e] - mx); s += p[e]; }
        float inv = 1.f / s;
#pragma unroll
        for (int e = 0; e < E_; ++e) p[e] *= inv;
        int b0 = 0; float v0 = p[0];
#pragma unroll
        for (int e = 1; e < E_; ++e) if (p[e] > v0) { v0 = p[e]; b0 = e; }
        int b1 = -1; float v1 = -1.f;
#pragma unroll
        for (int e = 0; e < E_; ++e) { if (e != b0 && p[e] > v1) { v1 = p[e]; b1 = e; } }
        float isum = 1.f / (v0 + v1);
        sel[wave*2]   = b0; sel[wave*2+1] = b1;
        wts[wave*2]   = v0 * isum; wts[wave*2+1] = v1 * isum;
    }
}

// ---------------- assign: deterministic positions, single block ----------------
__global__ void assign_kernel(const int* __restrict__ sel, const float* __restrict__ wts,
                              int* __restrict__ counts, int* __restrict__ offsets,
                              int* __restrict__ pos_of_slot, int* __restrict__ token_of,
                              float* __restrict__ slotw) {
    __shared__ int cnt[256][E_];
    __shared__ int offs[E_];
    int t = threadIdx.x;
    const int PER = NSLOT / 256;   // 32
    int base = t * PER;
    int loc[E_];
#pragma unroll
    for (int e = 0; e < E_; ++e) loc[e] = 0;
    for (int i = 0; i < PER; ++i) loc[sel[base + i]]++;
#pragma unroll
    for (int e = 0; e < E_; ++e) cnt[t][e] = loc[e];
    __syncthreads();
    if (t < E_) {
        int run = 0;
        for (int i = 0; i < 256; ++i) { int c = cnt[i][t]; cnt[i][t] = run; run += c; }
        counts[t] = run;
    }
    __syncthreads();
    if (t == 0) {
        int s = 0;
        for (int e = 0; e < E_; ++e) { offs[e] = s; offsets[e] = s; s += counts[e]; }
    }
    __syncthreads();
    int run[E_];
#pragma unroll
    for (int e = 0; e < E_; ++e) run[e] = offs[e] + cnt[t][e];
    for (int i = 0; i < PER; ++i) {
        int s = base + i;
        int e = sel[s];
        int p = run[e]++;
        pos_of_slot[s] = p;
        token_of[p] = s >> 1;
        slotw[p] = wts[s];
    }
}

// ---------------- copy: gather token rows to bf16 ----------------
__global__ void copy_kernel(const float* __restrict__ x, const int* __restrict__ pos_of_slot,
                            unsigned short* __restrict__ Xg) {
    int slot = blockIdx.x * 4 + (threadIdx.x >> 6);
    int lane = threadIdx.x & 63;
    int pos = pos_of_slot[slot];
    int n = slot >> 1;
    const float* xr = x + (size_t)n * C_;
    unsigned short* dst = Xg + (size_t)pos * C_;
#pragma unroll
    for (int i = 0; i < 4; ++i) {
        int c0 = i * 256 + lane * 4;
        float4 v = *(const float4*)(xr + c0);
        ushort4 b;
        b.x = f2bf(v.x); b.y = f2bf(v.y); b.z = f2bf(v.z); b.w = f2bf(v.w);
        *(ushort4*)(dst + c0) = b;
    }
}

// ---------------- wconv: per-expert transpose fp32 [R][Cc] -> bf16 [Cc][R] ----------------
__global__ void wconv_kernel(const float* __restrict__ src, unsigned short* __restrict__ dst,
                             int R, int Cc) {
    int e = blockIdx.z;
    int c0 = blockIdx.x * 64;
    int r0 = blockIdx.y * 64;
    const float* s = src + (size_t)e * R * Cc;
    unsigned short* d = dst + (size_t)e * R * Cc;
    __shared__ unsigned short t_[64][72];
    int t = threadIdx.x;
    int tr = t >> 4, tc4 = (t & 15) * 4;
#pragma unroll
    for (int i = 0; i < 4; ++i) {
        int r = tr + i * 16;
        float4 v = *(const float4*)(s + (size_t)(r0 + r) * Cc + c0 + tc4);
        t_[r][tc4+0] = f2bf(v.x); t_[r][tc4+1] = f2bf(v.y);
        t_[r][tc4+2] = f2bf(v.z); t_[r][tc4+3] = f2bf(v.w);
    }
    __syncthreads();
    int oc = t >> 2, seg = (t & 3) * 16;
    short8 w0, w1;
#pragma unroll
    for (int j = 0; j < 8; ++j) {
        w0[j] = (short)t_[seg + j][oc];
        w1[j] = (short)t_[seg + 8 + j][oc];
    }
    unsigned short* dp = d + (size_t)(c0 + oc) * R + r0 + seg;
    *(short8*)dp = w0;
    *(short8*)(dp + 8) = w1;
}

// ============ ring GEMMs v4: 128x128 tile, 4 waves, 2 BLOCKS/CU (TLP overlap) ============
// LDS: transposed 1024B blocks (block g = 16 rows x 4 chunks, chunk-major), staged per-lane
// (row=lane&15, chunk=lane>>4), dest linear -> conflict-free ds_read_b128.
// XCD swizzle: e = b&7 -> XCD x runs only expert x (L2 reuse of A panels, verified r7:
// FETCH 315->81MB). Counted-vmcnt ring, issue-invariant ledger w/ dummy tail re-stage.
// KEY CHANGE vs r5-r7: small blocks (72/64KB LDS, 256thr, launch_bounds(256,2)) so TWO
// blocks are resident per CU - one block's LDS/barrier window overlaps the other's MFMA
// window (m114 implicit overlap; all 1-block/CU designs stalled at ~4500cyc/phase).

#define G1_NH (C_/32)    // 32 K-halves

__global__ __launch_bounds__(256, 2) void gemm1_ring(
        const unsigned short* __restrict__ Xg, const unsigned short* __restrict__ W1t,
        const unsigned short* __restrict__ W3t, unsigned short* __restrict__ G,
        const int* __restrict__ counts, const int* __restrict__ offsets) {
    int b = blockIdx.y * 32 + blockIdx.x;   // [0, 8192)
    int e = b & 7;
    int j = b >> 3;                         // [0, 1024)
    int ct = j & 31;                        // 32 col tiles over H
    int rt = j >> 5;                        // [0, 32)
    int ne = counts[e];
    if (rt * 128 >= ne) return;
    int row0 = offsets[e] + rt * 128;
    int n0 = ct * 128;

    extern __shared__ char lds[];
    char* As  = lds;            // 3 slots x 8192 B (8 blocks of 1024B each)
    char* B1s = lds + 24576;    // 3 slots x 8192 B
    char* B3s = lds + 49152;    // 3 slots x 8192 B   (total 72KB)

    int tid = threadIdx.x, lane = tid & 63, wid = tid >> 6;   // 4 waves
    int wm = wid >> 1, wn = wid & 1;
    int fr = lane & 15, q = lane >> 4;
    int arow = lane & 15, akch = lane >> 4;   // staging lane map

    const unsigned short* Ap  = Xg + (size_t)row0 * C_;
    const unsigned short* B1p = W1t + ((size_t)e * H_ + n0) * C_;
    const unsigned short* B3p = W3t + ((size_t)e * H_ + n0) * C_;

    f32x4 acc1[4][4], acc3[4][4];
#pragma unroll
    for (int m = 0; m < 4; ++m)
#pragma unroll
        for (int n = 0; n < 4; ++n) {
            acc1[m][n] = (f32x4){0.f,0.f,0.f,0.f};
            acc3[m][n] = (f32x4){0.f,0.f,0.f,0.f};
        }

    auto STAGE = [&](int hs, int slot) {   // 6 loads/wave/half
        int k0 = hs * 32;
#pragma unroll
        for (int jj = 0; jj < 2; ++jj) {
            int g = wid + jj * 4;          // block index 0..7
            gload16(Ap  + (size_t)(g * 16 + arow) * C_ + k0 + akch * 8,
                    As  + slot * 8192 + g * 1024);
            gload16(B1p + (size_t)(g * 16 + arow) * C_ + k0 + akch * 8,
                    B1s + slot * 8192 + g * 1024);
            gload16(B3p + (size_t)(g * 16 + arow) * C_ + k0 + akch * 8,
                    B3s + slot * 8192 + g * 1024);
        }
    };

    STAGE(0, 0); STAGE(1, 1);       // 12 loads in flight
    WAITVM(6);                      // half 0 landed
    __builtin_amdgcn_s_barrier();

    for (int h = 0; h < G1_NH; ++h) {
        int slot = h % 3;
        int hs = (h + 2 < G1_NH) ? h + 2 : G1_NH - 1;   // tail: dummy re-stage
        int wslot = (h + 2) % 3;
        short8 a[4], b1[4], b3[4];
#pragma unroll
        for (int m = 0; m < 4; ++m)
            a[m] = *(const short8*)(As + slot * 8192 + (wm * 4 + m) * 1024 + q * 256 + fr * 16);
#pragma unroll
        for (int n = 0; n < 4; ++n) {
            b1[n] = *(const short8*)(B1s + slot * 8192 + (wn * 4 + n) * 1024 + q * 256 + fr * 16);
            b3[n] = *(const short8*)(B3s + slot * 8192 + (wn * 4 + n) * 1024 + q * 256 + fr * 16);
        }
        STAGE(hs, wslot);
        WAITVM(6);                  // retires half h+1 (issued 1 phase ago)
        __builtin_amdgcn_sched_barrier(0);
        __builtin_amdgcn_s_barrier();
        __builtin_amdgcn_s_setprio(1);
#pragma unroll
        for (int m = 0; m < 4; ++m)
#pragma unroll
            for (int n = 0; n < 4; ++n) {
                acc1[m][n] = __builtin_amdgcn_mfma_f32_16x16x32_bf16(a[m], b1[n], acc1[m][n], 0, 0, 0);
                acc3[m][n] = __builtin_amdgcn_mfma_f32_16x16x32_bf16(a[m], b3[n], acc3[m][n], 0, 0, 0);
            }
        __builtin_amdgcn_s_setprio(0);
        __builtin_amdgcn_s_barrier();
    }
    WAITVM(0);   // drain dummy staging before kernel end

    // epilogue: silu(h1)*h3 -> bf16 G
#pragma unroll
    for (int m = 0; m < 4; ++m)
#pragma unroll
        for (int rg = 0; rg < 4; ++rg) {
            int row = wm*64 + m*16 + q*4 + rg;
            if (rt * 128 + row < ne) {
                size_t gbase = (size_t)(row0 + row) * H_ + n0 + wn*64;
#pragma unroll
                for (int n = 0; n < 4; ++n) {
                    float h1 = acc1[m][n][rg];
                    float h3 = acc3[m][n][rg];
                    float g = h1 * h3 / (1.f + __expf(-h1));
                    G[gbase + n*16 + fr] = f2bf(g);
                }
            }
        }
}

#define G2_NH (H_/32)    // 128 K-halves

__global__ __launch_bounds__(256, 2) void gemm2_ring(
        const unsigned short* __restrict__ G, const unsigned short* __restrict__ W2t,
        float* __restrict__ out, const int* __restrict__ counts,
        const int* __restrict__ offsets, const int* __restrict__ token_of,
        const float* __restrict__ slotw) {
    int b = blockIdx.y * 8 + blockIdx.x;    // [0, 2048)
    int e = b & 7;
    int j = b >> 3;                         // [0, 256)
    int ct = j & 7;                         // 8 col tiles over C
    int rt = j >> 3;                        // [0, 32)
    int ne = counts[e];
    if (rt * 128 >= ne) return;
    int row0 = offsets[e] + rt * 128;
    int n0 = ct * 128;

    extern __shared__ char lds[];
    char* As = lds;             // 4 slots x 8192 B
    char* Bs = lds + 32768;     // 4 slots x 8192 B   (total 64KB)

    int tid = threadIdx.x, lane = tid & 63, wid = tid >> 6;   // 4 waves
    int wm = wid >> 1, wn = wid & 1;
    int fr = lane & 15, q = lane >> 4;
    int arow = lane & 15, akch = lane >> 4;

    const unsigned short* Ap = G + (size_t)row0 * H_;
    const unsigned short* Bp = W2t + ((size_t)e * C_ + n0) * H_;

    f32x4 acc[4][4];
#pragma unroll
    for (int m = 0; m < 4; ++m)
#pragma unroll
        for (int n = 0; n < 4; ++n) acc[m][n] = (f32x4){0.f,0.f,0.f,0.f};

    auto STAGE = [&](int hs, int slot) {   // 4 loads/wave/half
        int k0 = hs * 32;
#pragma unroll
        for (int jj = 0; jj < 2; ++jj) {
            int g = wid + jj * 4;
            gload16(Ap + (size_t)(g * 16 + arow) * H_ + k0 + akch * 8,
                    As + slot * 8192 + g * 1024);
            gload16(Bp + (size_t)(g * 16 + arow) * H_ + k0 + akch * 8,
                    Bs + slot * 8192 + g * 1024);
        }
    };

    STAGE(0, 0); STAGE(1, 1); STAGE(2, 2);   // 12 loads in flight
    WAITVM(8);                               // half 0 landed
    __builtin_amdgcn_s_barrier();

    for (int h = 0; h < G2_NH; ++h) {
        int slot = h & 3;
        int hs = (h + 3 < G2_NH) ? h + 3 : G2_NH - 1;   // tail: dummy re-stage
        short8 a[4], bfr[4];
#pragma unroll
        for (int m = 0; m < 4; ++m)
            a[m] = *(const short8*)(As + slot * 8192 + (wm * 4 + m) * 1024 + q * 256 + fr * 16);
#pragma unroll
        for (int n = 0; n < 4; ++n)
            bfr[n] = *(const short8*)(Bs + slot * 8192 + (wn * 4 + n) * 1024 + q * 256 + fr * 16);
        STAGE(hs, (h + 3) & 3);
        WAITVM(8);                           // retires half h+1 (issued 2 phases ago)
        __builtin_amdgcn_sched_barrier(0);
        __builtin_amdgcn_s_barrier();
        __builtin_amdgcn_s_setprio(1);
#pragma unroll
        for (int m = 0; m < 4; ++m)
#pragma unroll
            for (int n = 0; n < 4; ++n)
                acc[m][n] = __builtin_amdgcn_mfma_f32_16x16x32_bf16(a[m], bfr[n], acc[m][n], 0, 0, 0);
        __builtin_amdgcn_s_setprio(0);
        __builtin_amdgcn_s_barrier();
    }
    WAITVM(0);

    // epilogue: scatter-add weighted partial into out
#pragma unroll
    for (int m = 0; m < 4; ++m)
#pragma unroll
        for (int rg = 0; rg < 4; ++rg) {
            int row = wm*64 + m*16 + q*4 + rg;
            if (rt * 128 + row < ne) {
                int grow = row0 + row;
                int tok = token_of[grow];
                float w = slotw[grow];
                float* orow = out + (size_t)tok * C_ + n0 + wn*64;
#pragma unroll
                for (int n = 0; n < 4; ++n)
                    atomicAdd(orow + n*16 + fr, acc[m][n][rg] * w);
            }
        }
}

// ============ SLOW PATH (fallback if ws too small) ============
#define BM 128
#define BN 128
#define BK 32
__global__ __launch_bounds__(256, 2) void gemm1_slow(
        const unsigned short* __restrict__ Xg, const float* __restrict__ W1,
        const float* __restrict__ W3, unsigned short* __restrict__ G,
        const int* __restrict__ counts, const int* __restrict__ offsets) {
    int ct = blockIdx.x;
    int rslot = blockIdx.y;
    int e = rslot >> 5, rt = rslot & 31;
    int ne = counts[e];
    if (rt * BM >= ne) return;
    int row0 = offsets[e] + rt * BM;
    int n0 = ct * BN;

    __shared__ unsigned short As[BM][LPAD];
    __shared__ unsigned short B1s[BN][LPAD];
    __shared__ unsigned short B3s[BN][LPAD];

    int tid = threadIdx.x;
    int lane = tid & 63, wid = tid >> 6;
    int wr = (wid >> 1) * 64, wc = (wid & 1) * 64;

    f32x4 acc1[4][4], acc3[4][4];
#pragma unroll
    for (int m = 0; m < 4; ++m)
#pragma unroll
        for (int n = 0; n < 4; ++n) {
            acc1[m][n] = (f32x4){0.f,0.f,0.f,0.f};
            acc3[m][n] = (f32x4){0.f,0.f,0.f,0.f};
        }

    const float* B1p = W1 + (size_t)e * C_ * H_ + n0;
    const float* B3p = W3 + (size_t)e * C_ * H_ + n0;
    int chunk = tid & 3, rr = tid >> 2;
    int kq = tid >> 5, n4 = tid & 31;

    for (int k0 = 0; k0 < C_; k0 += BK) {
        __syncthreads();
#pragma unroll
        for (int h = 0; h < 2; ++h) {
            int row = rr + h * 64;
            uint4 v = *(const uint4*)(Xg + (size_t)(row0 + row) * C_ + k0 + chunk * 8);
            *(uint4*)&As[row][chunk * 8] = v;
        }
        {
            float4 r0 = *(const float4*)(B1p + (size_t)(k0 + kq*4 + 0) * H_ + n4*4);
            float4 r1 = *(const float4*)(B1p + (size_t)(k0 + kq*4 + 1) * H_ + n4*4);
            float4 r2 = *(const float4*)(B1p + (size_t)(k0 + kq*4 + 2) * H_ + n4*4);
            float4 r3 = *(const float4*)(B1p + (size_t)(k0 + kq*4 + 3) * H_ + n4*4);
            ushort4 w0 = {f2bf(r0.x), f2bf(r1.x), f2bf(r2.x), f2bf(r3.x)};
            ushort4 w1 = {f2bf(r0.y), f2bf(r1.y), f2bf(r2.y), f2bf(r3.y)};
            ushort4 w2 = {f2bf(r0.z), f2bf(r1.z), f2bf(r2.z), f2bf(r3.z)};
            ushort4 w3 = {f2bf(r0.w), f2bf(r1.w), f2bf(r2.w), f2bf(r3.w)};
            *(ushort4*)&B1s[n4*4+0][kq*4] = w0;
            *(ushort4*)&B1s[n4*4+1][kq*4] = w1;
            *(ushort4*)&B1s[n4*4+2][kq*4] = w2;
            *(ushort4*)&B1s[n4*4+3][kq*4] = w3;
            r0 = *(const float4*)(B3p + (size_t)(k0 + kq*4 + 0) * H_ + n4*4);
            r1 = *(const float4*)(B3p + (size_t)(k0 + kq*4 + 1) * H_ + n4*4);
            r2 = *(const float4*)(B3p + (size_t)(k0 + kq*4 + 2) * H_ + n4*4);
            r3 = *(const float4*)(B3p + (size_t)(k0 + kq*4 + 3) * H_ + n4*4);
            w0 = (ushort4){f2bf(r0.x), f2bf(r1.x), f2bf(r2.x), f2bf(r3.x)};
            w1 = (ushort4){f2bf(r0.y), f2bf(r1.y), f2bf(r2.y), f2bf(r3.y)};
            w2 = (ushort4){f2bf(r0.z), f2bf(r1.z), f2bf(r2.z), f2bf(r3.z)};
            w3 = (ushort4){f2bf(r0.w), f2bf(r1.w), f2bf(r2.w), f2bf(r3.w)};
            *(ushort4*)&B3s[n4*4+0][kq*4] = w0;
            *(ushort4*)&B3s[n4*4+1][kq*4] = w1;
            *(ushort4*)&B3s[n4*4+2][kq*4] = w2;
            *(ushort4*)&B3s[n4*4+3][kq*4] = w3;
        }
        __syncthreads();
        int q = lane >> 4, fr = lane & 15;
        short8 a[4], b1[4], b3[4];
#pragma unroll
        for (int m = 0; m < 4; ++m) a[m] = *(const short8*)&As[wr + m*16 + fr][q*8];
#pragma unroll
        for (int n = 0; n < 4; ++n) {
            b1[n] = *(const short8*)&B1s[wc + n*16 + fr][q*8];
            b3[n] = *(const short8*)&B3s[wc + n*16 + fr][q*8];
        }
#pragma unroll
        for (int m = 0; m < 4; ++m)
#pragma unroll
            for (int n = 0; n < 4; ++n) {
                acc1[m][n] = __builtin_amdgcn_mfma_f32_16x16x32_bf16(a[m], b1[n], acc1[m][n], 0, 0, 0);
                acc3[m][n] = __builtin_amdgcn_mfma_f32_16x16x32_bf16(a[m], b3[n], acc3[m][n], 0, 0, 0);
            }
    }
    int q = lane >> 4, cfr = lane & 15;
#pragma unroll
    for (int m = 0; m < 4; ++m) {
#pragma unroll
        for (int rg = 0; rg < 4; ++rg) {
            int row = wr + m*16 + q*4 + rg;
            if (rt * BM + row < ne) {
                size_t gbase = (size_t)(row0 + row) * H_ + n0;
#pragma unroll
                for (int n = 0; n < 4; ++n) {
                    float h1 = acc1[m][n][rg];
                    float h3 = acc3[m][n][rg];
                    float g = h1 * h3 / (1.f + __expf(-h1));
                    G[gbase + wc + n*16 + cfr] = f2bf(g);
                }
            }
        }
    }
}

__global__ __launch_bounds__(256, 2) void gemm2_slow(
        const unsigned short* __restrict__ G, const float* __restrict__ W2,
        float* __restrict__ out, const int* __restrict__ counts,
        const int* __restrict__ offsets, const int* __restrict__ token_of,
        const float* __restrict__ slotw) {
    int ct = blockIdx.x;
    int rslot = blockIdx.y;
    int e = rslot >> 5, rt = rslot & 31;
    int ne = counts[e];
    if (rt * BM >= ne) return;
    int row0 = offsets[e] + rt * BM;
    int n0 = ct * BN;

    __shared__ unsigned short As[BM][LPAD];
    __shared__ unsigned short Bs[BN][LPAD];

    int tid = threadIdx.x;
    int lane = tid & 63, wid = tid >> 6;
    int wr = (wid >> 1) * 64, wc = (wid & 1) * 64;

    f32x4 acc[4][4];
#pragma unroll
    for (int m = 0; m < 4; ++m)
#pragma unroll
        for (int n = 0; n < 4; ++n) acc[m][n] = (f32x4){0.f,0.f,0.f,0.f};

    const float* Bp = W2 + (size_t)e * H_ * C_ + n0;
    int chunk = tid & 3, rr = tid >> 2;
    int kq = tid >> 5, n4 = tid & 31;

    for (int k0 = 0; k0 < H_; k0 += BK) {
        __syncthreads();
#pragma unroll
        for (int h = 0; h < 2; ++h) {
            int row = rr + h * 64;
            uint4 v = *(const uint4*)(G + (size_t)(row0 + row) * H_ + k0 + chunk * 8);
            *(uint4*)&As[row][chunk * 8] = v;
        }
        {
            float4 r0 = *(const float4*)(Bp + (size_t)(k0 + kq*4 + 0) * C_ + n4*4);
            float4 r1 = *(const float4*)(Bp + (size_t)(k0 + kq*4 + 1) * C_ + n4*4);
            float4 r2 = *(const float4*)(Bp + (size_t)(k0 + kq*4 + 2) * C_ + n4*4);
            float4 r3 = *(const float4*)(Bp + (size_t)(k0 + kq*4 + 3) * C_ + n4*4);
            ushort4 w0 = {f2bf(r0.x), f2bf(r1.x), f2bf(r2.x), f2bf(r3.x)};
            ushort4 w1 = {f2bf(r0.y), f2bf(r1.y), f2bf(r2.y), f2bf(r3.y)};
            ushort4 w2 = {f2bf(r0.z), f2bf(r1.z), f2bf(r2.z), f2bf(r3.z)};
            ushort4 w3 = {f2bf(r0.w), f2bf(r1.w), f2bf(r2.w), f2bf(r3.w)};
            *(ushort4*)&Bs[n4*4+0][kq*4] = w0;
            *(ushort4*)&Bs[n4*4+1][kq*4] = w1;
            *(ushort4*)&Bs[n4*4+2][kq*4] = w2;
            *(ushort4*)&Bs[n4*4+3][kq*4] = w3;
        }
        __syncthreads();
        int q = lane >> 4, fr = lane & 15;
        short8 a[4], b[4];
#pragma unroll
        for (int m = 0; m < 4; ++m) a[m] = *(const short8*)&As[wr + m*16 + fr][q*8];
#pragma unroll
        for (int n = 0; n < 4; ++n) b[n] = *(const short8*)&Bs[wc + n*16 + fr][q*8];
#pragma unroll
        for (int m = 0; m < 4; ++m)
#pragma unroll
            for (int n = 0; n < 4; ++n)
                acc[m][n] = __builtin_amdgcn_mfma_f32_16x16x32_bf16(a[m], b[n], acc[m][n], 0, 0, 0);
    }
    int q = lane >> 4, cfr = lane & 15;
#pragma unroll
    for (int m = 0; m < 4; ++m) {
#pragma unroll
        for (int rg = 0; rg < 4; ++rg) {
            int row = wr + m*16 + q*4 + rg;
            if (rt * BM + row < ne) {
                int grow = row0 + row;
                int tok = token_of[grow];
                float w = slotw[grow];
                float* orow = out + (size_t)tok * C_ + n0;
#pragma unroll
                for (int n = 0; n < 4; ++n)
                    atomicAdd(orow + wc + n*16 + cfr, acc[m][n][rg] * w);
            }
        }
    }
}

extern "C" void kernel_launch(void* const* d_in, const int* in_sizes, int n_in,
                              void* d_out, int out_size, void* d_ws, size_t ws_size,
                              hipStream_t stream) {
    const float* x  = (const float*)d_in[0];
    const float* Wg = (const float*)d_in[1];
    const float* W1 = (const float*)d_in[2];
    const float* W2 = (const float*)d_in[3];
    const float* W3 = (const float*)d_in[4];
    float* out = (float*)d_out;

    char* ws = (char*)d_ws;
    size_t o = 0;
    int*   sel      = (int*)(ws + o);  o += (size_t)NSLOT * 4;
    float* wts      = (float*)(ws + o); o += (size_t)NSLOT * 4;
    int*   pos      = (int*)(ws + o);  o += (size_t)NSLOT * 4;
    int*   token_of = (int*)(ws + o);  o += (size_t)NSLOT * 4;
    float* slotw    = (float*)(ws + o); o += (size_t)NSLOT * 4;
    int*   counts   = (int*)(ws + o);
    int*   offsets  = counts + E_;     o += 256;
    unsigned short* Xg = (unsigned short*)(ws + o); o += (size_t)SPAD * C_ * 2;
    unsigned short* G  = (unsigned short*)(ws + o); o += (size_t)SPAD * H_ * 2;
    size_t need_slow = o;
    unsigned short* W1t = (unsigned short*)(ws + o); o += (size_t)E_ * H_ * C_ * 2;
    unsigned short* W3t = (unsigned short*)(ws + o); o += (size_t)E_ * H_ * C_ * 2;
    unsigned short* W2t = W1t;   // W1t region freed after gemm1
    size_t need_fast = o;

    hipMemsetAsync(d_out, 0, (size_t)out_size * sizeof(float), stream);
    if (ws_size < need_slow) return;

    router_kernel<<<N_TOK/4, 256, 0, stream>>>(x, Wg, sel, wts);
    assign_kernel<<<1, 256, 0, stream>>>(sel, wts, counts, offsets, pos, token_of, slotw);
    copy_kernel<<<NSLOT/4, 256, 0, stream>>>(x, pos, Xg);

    if (ws_size >= need_fast) {
        hipFuncSetAttribute((const void*)gemm1_ring, hipFuncAttributeMaxDynamicSharedMemorySize, 73728);
        hipFuncSetAttribute((const void*)gemm2_ring, hipFuncAttributeMaxDynamicSharedMemorySize, 65536);
        wconv_kernel<<<dim3(H_/64, C_/64, E_), 256, 0, stream>>>(W1, W1t, C_, H_);
        wconv_kernel<<<dim3(H_/64, C_/64, E_), 256, 0, stream>>>(W3, W3t, C_, H_);
        gemm1_ring<<<dim3(32, 256), 256, 73728, stream>>>(Xg, W1t, W3t, G, counts, offsets);
        wconv_kernel<<<dim3(C_/64, H_/64, E_), 256, 0, stream>>>(W2, W2t, H_, C_);
        gemm2_ring<<<dim3(8, 256), 256, 65536, stream>>>(G, W2t, out, counts, offsets, token_of, slotw);
    } else {
        gemm1_slow<<<dim3(H_/BN, E_*32), 256, 0, stream>>>(Xg, W1, W3, G, counts, offsets);
        gemm2_slow<<<dim3(C_/BN, E_*32), 256, 0, stream>>>(G, W2, out, counts, offsets, token_of, slotw);
    }
}

// Round 9
// 584.978 us; speedup vs baseline: 1.0162x; 1.0084x over previous
//
#include <hip/hip_runtime.h>
#include <hip/hip_bf16.h>

#define E_     8
#define C_     1024
#define H_     4096
#define N_TOK  4096
#define TOPK   2
#define NSLOT  (N_TOK*TOPK)   // 8192
#define SPAD   (NSLOT+256)    // padded rows for 256-row tile-tail reads

#define LPAD 40               // slow-path LDS row stride

typedef __attribute__((ext_vector_type(4))) float f32x4;
typedef __attribute__((ext_vector_type(8))) short short8;

__device__ __forceinline__ unsigned short f2bf(float f) {
    return __builtin_bit_cast(unsigned short, __float2bfloat16(f));
}

__device__ __forceinline__ void gload16(const void* g, const void* l) {
    __builtin_amdgcn_global_load_lds(
        (const __attribute__((address_space(1))) unsigned int*)g,
        (__attribute__((address_space(3))) unsigned int*)l, 16, 0, 0);
}

#define WAITVM_(n) asm volatile("s_waitcnt vmcnt(" #n ")" ::: "memory")
#define WAITVM(n) WAITVM_(n)

// ---------------- router: 1 wave per token (no atomics) ----------------
__global__ void router_kernel(const float* __restrict__ x, const float* __restrict__ Wg,
                              int* __restrict__ sel, float* __restrict__ wts) {
    int wave = (blockIdx.x * blockDim.x + threadIdx.x) >> 6;
    int lane = threadIdx.x & 63;
    if (wave >= N_TOK) return;
    const float* xr = x + (size_t)wave * C_;
    float acc[E_];
#pragma unroll
    for (int e = 0; e < E_; ++e) acc[e] = 0.f;
    for (int c = lane; c < C_; c += 64) {
        float xv = xr[c];
#pragma unroll
        for (int e = 0; e < E_; ++e) acc[e] += xv * Wg[e * C_ + c];
    }
#pragma unroll
    for (int e = 0; e < E_; ++e) {
#pragma unroll
        for (int off = 32; off > 0; off >>= 1) acc[e] += __shfl_xor(acc[e], off);
    }
    if (lane == 0) {
        float mx = acc[0];
#pragma unroll
        for (int e = 1; e < E_; ++e) mx = fmaxf(mx, acc[e]);
        float p[E_]; float s = 0.f;
#pragma unroll
        for (int e = 0; e < E_; ++e) { p[e] = __expf(acc[e] - mx); s += p[e]; }
        float inv = 1.f / s;
#pragma unroll
        for (int e = 0; e < E_; ++e) p[e] *= inv;
        int b0 = 0; float v0 = p[0];
#pragma unroll
        for (int e = 1; e < E_; ++e) if (p[e] > v0) { v0 = p[e]; b0 = e; }
        int b1 = -1; float v1 = -1.f;
#pragma unroll
        for (int e = 0; e < E_; ++e) { if (e != b0 && p[e] > v1) { v1 = p[e]; b1 = e; } }
        float isum = 1.f / (v0 + v1);
        sel[wave*2]   = b0; sel[wave*2+1] = b1;
        wts[wave*2]   = v0 * isum; wts[wave*2+1] = v1 * isum;
    }
}

// ---------------- assign: deterministic positions, single block ----------------
__global__ void assign_kernel(const int* __restrict__ sel, const float* __restrict__ wts,
                              int* __restrict__ counts, int* __restrict__ offsets,
                              int* __restrict__ pos_of_slot, int* __restrict__ token_of,
                              float* __restrict__ slotw) {
    __shared__ int cnt[256][E_];
    __shared__ int offs[E_];
    int t = threadIdx.x;
    const int PER = NSLOT / 256;   // 32
    int base = t * PER;
    int loc[E_];
#pragma unroll
    for (int e = 0; e < E_; ++e) loc[e] = 0;
    for (int i = 0; i < PER; ++i) loc[sel[base + i]]++;
#pragma unroll
    for (int e = 0; e < E_; ++e) cnt[t][e] = loc[e];
    __syncthreads();
    if (t < E_) {
        int run = 0;
        for (int i = 0; i < 256; ++i) { int c = cnt[i][t]; cnt[i][t] = run; run += c; }
        counts[t] = run;
    }
    __syncthreads();
    if (t == 0) {
        int s = 0;
        for (int e = 0; e < E_; ++e) { offs[e] = s; offsets[e] = s; s += counts[e]; }
    }
    __syncthreads();
    int run[E_];
#pragma unroll
    for (int e = 0; e < E_; ++e) run[e] = offs[e] + cnt[t][e];
    for (int i = 0; i < PER; ++i) {
        int s = base + i;
        int e = sel[s];
        int p = run[e]++;
        pos_of_slot[s] = p;
        token_of[p] = s >> 1;
        slotw[p] = wts[s];
    }
}

// ---------------- copy: gather token rows to bf16 ----------------
__global__ void copy_kernel(const float* __restrict__ x, const int* __restrict__ pos_of_slot,
                            unsigned short* __restrict__ Xg) {
    int slot = blockIdx.x * 4 + (threadIdx.x >> 6);
    int lane = threadIdx.x & 63;
    int pos = pos_of_slot[slot];
    int n = slot >> 1;
    const float* xr = x + (size_t)n * C_;
    unsigned short* dst = Xg + (size_t)pos * C_;
#pragma unroll
    for (int i = 0; i < 4; ++i) {
        int c0 = i * 256 + lane * 4;
        float4 v = *(const float4*)(xr + c0);
        ushort4 b;
        b.x = f2bf(v.x); b.y = f2bf(v.y); b.z = f2bf(v.z); b.w = f2bf(v.w);
        *(ushort4*)(dst + c0) = b;
    }
}

// ---------------- wconv: per-expert transpose fp32 [R][Cc] -> bf16 [Cc][R] ----------------
__global__ void wconv_kernel(const float* __restrict__ src, unsigned short* __restrict__ dst,
                             int R, int Cc) {
    int e = blockIdx.z;
    int c0 = blockIdx.x * 64;
    int r0 = blockIdx.y * 64;
    const float* s = src + (size_t)e * R * Cc;
    unsigned short* d = dst + (size_t)e * R * Cc;
    __shared__ unsigned short t_[64][72];
    int t = threadIdx.x;
    int tr = t >> 4, tc4 = (t & 15) * 4;
#pragma unroll
    for (int i = 0; i < 4; ++i) {
        int r = tr + i * 16;
        float4 v = *(const float4*)(s + (size_t)(r0 + r) * Cc + c0 + tc4);
        t_[r][tc4+0] = f2bf(v.x); t_[r][tc4+1] = f2bf(v.y);
        t_[r][tc4+2] = f2bf(v.z); t_[r][tc4+3] = f2bf(v.w);
    }
    __syncthreads();
    int oc = t >> 2, seg = (t & 3) * 16;
    short8 w0, w1;
#pragma unroll
    for (int j = 0; j < 8; ++j) {
        w0[j] = (short)t_[seg + j][oc];
        w1[j] = (short)t_[seg + 8 + j][oc];
    }
    unsigned short* dp = d + (size_t)(c0 + oc) * R + r0 + seg;
    *(short8*)dp = w0;
    *(short8*)(dp + 8) = w1;
}

// ============ ring GEMMs v5: 256x128 tile, 8 waves, 4-buf ring, ONE barrier/K-tile ============
// K-tile = 32. LDS: transposed 1024B blocks (16 rows x 4 chunks of 16B, chunk-major),
// staged per-lane (row=lane&15, chunk=lane>>4), dest linear -> conflict-free ds_read_b128
// (0 conflicts verified r6). Expert-pinned XCD swizzle (4x fetch cut verified r7).
// Loop t: { STAGE(t+2 -> buf (t+2)&3); WAITVM(counted); s_barrier; reads+MFMA free-run }.
//   RAW: each wave vmcnts its OWN loads then barriers -> after barrier all waves' tile-t
//        loads are retired.   WAR: staged buf's last reader was tile t-2, >=1 barrier ago.
//   Ledger (4 loads/wave/tile g1, 3 g2): out at wait = 3 tiles in flight -> vmcnt(8)/(6),
//   never drains; dummy tail re-stage keeps it issue-invariant.
// KEY CHANGE vs r4 (8 barriers + 4 vmcnt per K-tile): waves free-run within the tile, so
// one wave's ds_reads overlap another's MFMA -- r4's 2.9x-of-MFMA-floor lockstep removed.

#define G1_NT (C_/32)    // 32 K-tiles

__global__ __launch_bounds__(512, 2) void gemm1_ring(
        const unsigned short* __restrict__ Xg, const unsigned short* __restrict__ W1t,
        const unsigned short* __restrict__ W3t, unsigned short* __restrict__ G,
        const int* __restrict__ counts, const int* __restrict__ offsets) {
    int b = blockIdx.y * 32 + blockIdx.x;   // [0, 8192)
    int e = b & 7;
    int j = b >> 3;                         // [0, 1024)
    int ct = j & 31;                        // 32 col tiles over H
    int rt = j >> 5;                        // [0, 32)
    int ne = counts[e];
    if (rt * 256 >= ne) return;
    int row0 = offsets[e] + rt * 256;
    int n0 = ct * 128;

    extern __shared__ char lds[];
    char* As  = lds;             // 4 bufs x 16384 B (16 blocks of 1024B)
    char* B1s = lds + 65536;     // 4 bufs x 8192 B  (8 blocks)
    char* B3s = lds + 98304;     // 4 bufs x 8192 B   (total 128KB)

    int tid = threadIdx.x, lane = tid & 63, wid = tid >> 6;   // 8 waves (4M x 2N)
    int wm = wid >> 1, wn = wid & 1;
    int fr = lane & 15, q = lane >> 4;
    int arow = lane & 15, akch = lane >> 4;   // staging lane map

    const unsigned short* Ap  = Xg + (size_t)row0 * C_;
    const unsigned short* B1p = W1t + ((size_t)e * H_ + n0) * C_;
    const unsigned short* B3p = W3t + ((size_t)e * H_ + n0) * C_;

    f32x4 acc1[4][4], acc3[4][4];
#pragma unroll
    for (int m = 0; m < 4; ++m)
#pragma unroll
        for (int n = 0; n < 4; ++n) {
            acc1[m][n] = (f32x4){0.f,0.f,0.f,0.f};
            acc3[m][n] = (f32x4){0.f,0.f,0.f,0.f};
        }

    auto STAGE = [&](int ts, int buf) {   // 4 loads/wave/tile
        int k0 = ts * 32;
#pragma unroll
        for (int jj = 0; jj < 2; ++jj) {
            int ab = wid * 2 + jj;         // A block 0..15
            gload16(Ap + (size_t)(ab * 16 + arow) * C_ + k0 + akch * 8,
                    As + buf * 16384 + ab * 1024);
        }
        gload16(B1p + (size_t)(wid * 16 + arow) * C_ + k0 + akch * 8,
                B1s + buf * 8192 + wid * 1024);
        gload16(B3p + (size_t)(wid * 16 + arow) * C_ + k0 + akch * 8,
                B3s + buf * 8192 + wid * 1024);
    };

    STAGE(0, 0); STAGE(1, 1);       // 8 loads in flight
    for (int t = 0; t < G1_NT; ++t) {
        int ts = (t + 2 < G1_NT) ? t + 2 : G1_NT - 1;   // tail: dummy re-stage
        STAGE(ts, (t + 2) & 3);
        WAITVM(8);                  // retire tile t's loads (12 outstanding -> 8)
        __builtin_amdgcn_s_barrier();
        __builtin_amdgcn_sched_barrier(0);
        int buf = t & 3;
        short8 a[4], bb[4];
#pragma unroll
        for (int m = 0; m < 4; ++m)
            a[m] = *(const short8*)(As + buf * 16384 + (wm * 4 + m) * 1024 + q * 256 + fr * 16);
#pragma unroll
        for (int n = 0; n < 4; ++n)
            bb[n] = *(const short8*)(B1s + buf * 8192 + (wn * 4 + n) * 1024 + q * 256 + fr * 16);
        __builtin_amdgcn_s_setprio(1);
#pragma unroll
        for (int m = 0; m < 4; ++m)
#pragma unroll
            for (int n = 0; n < 4; ++n)
                acc1[m][n] = __builtin_amdgcn_mfma_f32_16x16x32_bf16(a[m], bb[n], acc1[m][n], 0, 0, 0);
        __builtin_amdgcn_s_setprio(0);
#pragma unroll
        for (int n = 0; n < 4; ++n)
            bb[n] = *(const short8*)(B3s + buf * 8192 + (wn * 4 + n) * 1024 + q * 256 + fr * 16);
        __builtin_amdgcn_s_setprio(1);
#pragma unroll
        for (int m = 0; m < 4; ++m)
#pragma unroll
            for (int n = 0; n < 4; ++n)
                acc3[m][n] = __builtin_amdgcn_mfma_f32_16x16x32_bf16(a[m], bb[n], acc3[m][n], 0, 0, 0);
        __builtin_amdgcn_s_setprio(0);
    }
    WAITVM(0);   // drain dummy staging before epilogue / kernel end

    // epilogue: silu(h1)*h3 -> bf16 G
#pragma unroll
    for (int m = 0; m < 4; ++m)
#pragma unroll
        for (int rg = 0; rg < 4; ++rg) {
            int row = wm*64 + m*16 + q*4 + rg;
            if (rt * 256 + row < ne) {
                size_t gbase = (size_t)(row0 + row) * H_ + n0 + wn*64;
#pragma unroll
                for (int n = 0; n < 4; ++n) {
                    float h1 = acc1[m][n][rg];
                    float h3 = acc3[m][n][rg];
                    float g = h1 * h3 / (1.f + __expf(-h1));
                    G[gbase + n*16 + fr] = f2bf(g);
                }
            }
        }
}

#define G2_NT (H_/32)    // 128 K-tiles

__global__ __launch_bounds__(512, 2) void gemm2_ring(
        const unsigned short* __restrict__ G, const unsigned short* __restrict__ W2t,
        float* __restrict__ out, const int* __restrict__ counts,
        const int* __restrict__ offsets, const int* __restrict__ token_of,
        const float* __restrict__ slotw) {
    int b = blockIdx.y * 8 + blockIdx.x;    // [0, 2048)
    int e = b & 7;
    int j = b >> 3;                         // [0, 256)
    int ct = j & 7;                         // 8 col tiles over C
    int rt = j >> 3;                        // [0, 32)
    int ne = counts[e];
    if (rt * 256 >= ne) return;
    int row0 = offsets[e] + rt * 256;
    int n0 = ct * 128;

    extern __shared__ char lds[];
    char* As = lds;             // 4 bufs x 16384 B
    char* Bs = lds + 65536;     // 4 bufs x 8192 B   (total 96KB)

    int tid = threadIdx.x, lane = tid & 63, wid = tid >> 6;
    int wm = wid >> 1, wn = wid & 1;
    int fr = lane & 15, q = lane >> 4;
    int arow = lane & 15, akch = lane >> 4;

    const unsigned short* Ap = G + (size_t)row0 * H_;
    const unsigned short* Bp = W2t + ((size_t)e * C_ + n0) * H_;

    f32x4 acc[4][4];
#pragma unroll
    for (int m = 0; m < 4; ++m)
#pragma unroll
        for (int n = 0; n < 4; ++n) acc[m][n] = (f32x4){0.f,0.f,0.f,0.f};

    auto STAGE = [&](int ts, int buf) {   // 3 loads/wave/tile
        int k0 = ts * 32;
#pragma unroll
        for (int jj = 0; jj < 2; ++jj) {
            int ab = wid * 2 + jj;
            gload16(Ap + (size_t)(ab * 16 + arow) * H_ + k0 + akch * 8,
                    As + buf * 16384 + ab * 1024);
        }
        gload16(Bp + (size_t)(wid * 16 + arow) * H_ + k0 + akch * 8,
                Bs + buf * 8192 + wid * 1024);
    };

    STAGE(0, 0); STAGE(1, 1);       // 6 loads in flight
    for (int t = 0; t < G2_NT; ++t) {
        int ts = (t + 2 < G2_NT) ? t + 2 : G2_NT - 1;   // tail: dummy re-stage
        STAGE(ts, (t + 2) & 3);
        WAITVM(6);                  // retire tile t's loads (9 outstanding -> 6)
        __builtin_amdgcn_s_barrier();
        __builtin_amdgcn_sched_barrier(0);
        int buf = t & 3;
        short8 a[4], bb[4];
#pragma unroll
        for (int m = 0; m < 4; ++m)
            a[m] = *(const short8*)(As + buf * 16384 + (wm * 4 + m) * 1024 + q * 256 + fr * 16);
#pragma unroll
        for (int n = 0; n < 4; ++n)
            bb[n] = *(const short8*)(Bs + buf * 8192 + (wn * 4 + n) * 1024 + q * 256 + fr * 16);
        __builtin_amdgcn_s_setprio(1);
#pragma unroll
        for (int m = 0; m < 4; ++m)
#pragma unroll
            for (int n = 0; n < 4; ++n)
                acc[m][n] = __builtin_amdgcn_mfma_f32_16x16x32_bf16(a[m], bb[n], acc[m][n], 0, 0, 0);
        __builtin_amdgcn_s_setprio(0);
    }
    WAITVM(0);

    // epilogue: scatter-add weighted partial into out
#pragma unroll
    for (int m = 0; m < 4; ++m)
#pragma unroll
        for (int rg = 0; rg < 4; ++rg) {
            int row = wm*64 + m*16 + q*4 + rg;
            if (rt * 256 + row < ne) {
                int grow = row0 + row;
                int tok = token_of[grow];
                float w = slotw[grow];
                float* orow = out + (size_t)tok * C_ + n0 + wn*64;
#pragma unroll
                for (int n = 0; n < 4; ++n)
                    atomicAdd(orow + n*16 + fr, acc[m][n][rg] * w);
            }
        }
}

// ============ SLOW PATH (fallback if ws too small) ============
#define BM 128
#define BN 128
#define BK 32
__global__ __launch_bounds__(256, 2) void gemm1_slow(
        const unsigned short* __restrict__ Xg, const float* __restrict__ W1,
        const float* __restrict__ W3, unsigned short* __restrict__ G,
        const int* __restrict__ counts, const int* __restrict__ offsets) {
    int ct = blockIdx.x;
    int rslot = blockIdx.y;
    int e = rslot >> 5, rt = rslot & 31;
    int ne = counts[e];
    if (rt * BM >= ne) return;
    int row0 = offsets[e] + rt * BM;
    int n0 = ct * BN;

    __shared__ unsigned short As[BM][LPAD];
    __shared__ unsigned short B1s[BN][LPAD];
    __shared__ unsigned short B3s[BN][LPAD];

    int tid = threadIdx.x;
    int lane = tid & 63, wid = tid >> 6;
    int wr = (wid >> 1) * 64, wc = (wid & 1) * 64;

    f32x4 acc1[4][4], acc3[4][4];
#pragma unroll
    for (int m = 0; m < 4; ++m)
#pragma unroll
        for (int n = 0; n < 4; ++n) {
            acc1[m][n] = (f32x4){0.f,0.f,0.f,0.f};
            acc3[m][n] = (f32x4){0.f,0.f,0.f,0.f};
        }

    const float* B1p = W1 + (size_t)e * C_ * H_ + n0;
    const float* B3p = W3 + (size_t)e * C_ * H_ + n0;
    int chunk = tid & 3, rr = tid >> 2;
    int kq = tid >> 5, n4 = tid & 31;

    for (int k0 = 0; k0 < C_; k0 += BK) {
        __syncthreads();
#pragma unroll
        for (int h = 0; h < 2; ++h) {
            int row = rr + h * 64;
            uint4 v = *(const uint4*)(Xg + (size_t)(row0 + row) * C_ + k0 + chunk * 8);
            *(uint4*)&As[row][chunk * 8] = v;
        }
        {
            float4 r0 = *(const float4*)(B1p + (size_t)(k0 + kq*4 + 0) * H_ + n4*4);
            float4 r1 = *(const float4*)(B1p + (size_t)(k0 + kq*4 + 1) * H_ + n4*4);
            float4 r2 = *(const float4*)(B1p + (size_t)(k0 + kq*4 + 2) * H_ + n4*4);
            float4 r3 = *(const float4*)(B1p + (size_t)(k0 + kq*4 + 3) * H_ + n4*4);
            ushort4 w0 = {f2bf(r0.x), f2bf(r1.x), f2bf(r2.x), f2bf(r3.x)};
            ushort4 w1 = {f2bf(r0.y), f2bf(r1.y), f2bf(r2.y), f2bf(r3.y)};
            ushort4 w2 = {f2bf(r0.z), f2bf(r1.z), f2bf(r2.z), f2bf(r3.z)};
            ushort4 w3 = {f2bf(r0.w), f2bf(r1.w), f2bf(r2.w), f2bf(r3.w)};
            *(ushort4*)&B1s[n4*4+0][kq*4] = w0;
            *(ushort4*)&B1s[n4*4+1][kq*4] = w1;
            *(ushort4*)&B1s[n4*4+2][kq*4] = w2;
            *(ushort4*)&B1s[n4*4+3][kq*4] = w3;
            r0 = *(const float4*)(B3p + (size_t)(k0 + kq*4 + 0) * H_ + n4*4);
            r1 = *(const float4*)(B3p + (size_t)(k0 + kq*4 + 1) * H_ + n4*4);
            r2 = *(const float4*)(B3p + (size_t)(k0 + kq*4 + 2) * H_ + n4*4);
            r3 = *(const float4*)(B3p + (size_t)(k0 + kq*4 + 3) * H_ + n4*4);
            w0 = (ushort4){f2bf(r0.x), f2bf(r1.x), f2bf(r2.x), f2bf(r3.x)};
            w1 = (ushort4){f2bf(r0.y), f2bf(r1.y), f2bf(r2.y), f2bf(r3.y)};
            w2 = (ushort4){f2bf(r0.z), f2bf(r1.z), f2bf(r2.z), f2bf(r3.z)};
            w3 = (ushort4){f2bf(r0.w), f2bf(r1.w), f2bf(r2.w), f2bf(r3.w)};
            *(ushort4*)&B3s[n4*4+0][kq*4] = w0;
            *(ushort4*)&B3s[n4*4+1][kq*4] = w1;
            *(ushort4*)&B3s[n4*4+2][kq*4] = w2;
            *(ushort4*)&B3s[n4*4+3][kq*4] = w3;
        }
        __syncthreads();
        int q = lane >> 4, fr = lane & 15;
        short8 a[4], b1[4], b3[4];
#pragma unroll
        for (int m = 0; m < 4; ++m) a[m] = *(const short8*)&As[wr + m*16 + fr][q*8];
#pragma unroll
        for (int n = 0; n < 4; ++n) {
            b1[n] = *(const short8*)&B1s[wc + n*16 + fr][q*8];
            b3[n] = *(const short8*)&B3s[wc + n*16 + fr][q*8];
        }
#pragma unroll
        for (int m = 0; m < 4; ++m)
#pragma unroll
            for (int n = 0; n < 4; ++n) {
                acc1[m][n] = __builtin_amdgcn_mfma_f32_16x16x32_bf16(a[m], b1[n], acc1[m][n], 0, 0, 0);
                acc3[m][n] = __builtin_amdgcn_mfma_f32_16x16x32_bf16(a[m], b3[n], acc3[m][n], 0, 0, 0);
            }
    }
    int q = lane >> 4, cfr = lane & 15;
#pragma unroll
    for (int m = 0; m < 4; ++m) {
#pragma unroll
        for (int rg = 0; rg < 4; ++rg) {
            int row = wr + m*16 + q*4 + rg;
            if (rt * BM + row < ne) {
                size_t gbase = (size_t)(row0 + row) * H_ + n0;
#pragma unroll
                for (int n = 0; n < 4; ++n) {
                    float h1 = acc1[m][n][rg];
                    float h3 = acc3[m][n][rg];
                    float g = h1 * h3 / (1.f + __expf(-h1));
                    G[gbase + wc + n*16 + cfr] = f2bf(g);
                }
            }
        }
    }
}

__global__ __launch_bounds__(256, 2) void gemm2_slow(
        const unsigned short* __restrict__ G, const float* __restrict__ W2,
        float* __restrict__ out, const int* __restrict__ counts,
        const int* __restrict__ offsets, const int* __restrict__ token_of,
        const float* __restrict__ slotw) {
    int ct = blockIdx.x;
    int rslot = blockIdx.y;
    int e = rslot >> 5, rt = rslot & 31;
    int ne = counts[e];
    if (rt * BM >= ne) return;
    int row0 = offsets[e] + rt * BM;
    int n0 = ct * BN;

    __shared__ unsigned short As[BM][LPAD];
    __shared__ unsigned short Bs[BN][LPAD];

    int tid = threadIdx.x;
    int lane = tid & 63, wid = tid >> 6;
    int wr = (wid >> 1) * 64, wc = (wid & 1) * 64;

    f32x4 acc[4][4];
#pragma unroll
    for (int m = 0; m < 4; ++m)
#pragma unroll
        for (int n = 0; n < 4; ++n) acc[m][n] = (f32x4){0.f,0.f,0.f,0.f};

    const float* Bp = W2 + (size_t)e * H_ * C_ + n0;
    int chunk = tid & 3, rr = tid >> 2;
    int kq = tid >> 5, n4 = tid & 31;

    for (int k0 = 0; k0 < H_; k0 += BK) {
        __syncthreads();
#pragma unroll
        for (int h = 0; h < 2; ++h) {
            int row = rr + h * 64;
            uint4 v = *(const uint4*)(G + (size_t)(row0 + row) * H_ + k0 + chunk * 8);
            *(uint4*)&As[row][chunk * 8] = v;
        }
        {
            float4 r0 = *(const float4*)(Bp + (size_t)(k0 + kq*4 + 0) * C_ + n4*4);
            float4 r1 = *(const float4*)(Bp + (size_t)(k0 + kq*4 + 1) * C_ + n4*4);
            float4 r2 = *(const float4*)(Bp + (size_t)(k0 + kq*4 + 2) * C_ + n4*4);
            float4 r3 = *(const float4*)(Bp + (size_t)(k0 + kq*4 + 3) * C_ + n4*4);
            ushort4 w0 = {f2bf(r0.x), f2bf(r1.x), f2bf(r2.x), f2bf(r3.x)};
            ushort4 w1 = {f2bf(r0.y), f2bf(r1.y), f2bf(r2.y), f2bf(r3.y)};
            ushort4 w2 = {f2bf(r0.z), f2bf(r1.z), f2bf(r2.z), f2bf(r3.z)};
            ushort4 w3 = {f2bf(r0.w), f2bf(r1.w), f2bf(r2.w), f2bf(r3.w)};
            *(ushort4*)&Bs[n4*4+0][kq*4] = w0;
            *(ushort4*)&Bs[n4*4+1][kq*4] = w1;
            *(ushort4*)&Bs[n4*4+2][kq*4] = w2;
            *(ushort4*)&Bs[n4*4+3][kq*4] = w3;
        }
        __syncthreads();
        int q = lane >> 4, fr = lane & 15;
        short8 a[4], b[4];
#pragma unroll
        for (int m = 0; m < 4; ++m) a[m] = *(const short8*)&As[wr + m*16 + fr][q*8];
#pragma unroll
        for (int n = 0; n < 4; ++n) b[n] = *(const short8*)&Bs[wc + n*16 + fr][q*8];
#pragma unroll
        for (int m = 0; m < 4; ++m)
#pragma unroll
            for (int n = 0; n < 4; ++n)
                acc[m][n] = __builtin_amdgcn_mfma_f32_16x16x32_bf16(a[m], b[n], acc[m][n], 0, 0, 0);
    }
    int q = lane >> 4, cfr = lane & 15;
#pragma unroll
    for (int m = 0; m < 4; ++m) {
#pragma unroll
        for (int rg = 0; rg < 4; ++rg) {
            int row = wr + m*16 + q*4 + rg;
            if (rt * BM + row < ne) {
                int grow = row0 + row;
                int tok = token_of[grow];
                float w = slotw[grow];
                float* orow = out + (size_t)tok * C_ + n0;
#pragma unroll
                for (int n = 0; n < 4; ++n)
                    atomicAdd(orow + wc + n*16 + cfr, acc[m][n][rg] * w);
            }
        }
    }
}

extern "C" void kernel_launch(void* const* d_in, const int* in_sizes, int n_in,
                              void* d_out, int out_size, void* d_ws, size_t ws_size,
                              hipStream_t stream) {
    const float* x  = (const float*)d_in[0];
    const float* Wg = (const float*)d_in[1];
    const float* W1 = (const float*)d_in[2];
    const float* W2 = (const float*)d_in[3];
    const float* W3 = (const float*)d_in[4];
    float* out = (float*)d_out;

    char* ws = (char*)d_ws;
    size_t o = 0;
    int*   sel      = (int*)(ws + o);  o += (size_t)NSLOT * 4;
    float* wts      = (float*)(ws + o); o += (size_t)NSLOT * 4;
    int*   pos      = (int*)(ws + o);  o += (size_t)NSLOT * 4;
    int*   token_of = (int*)(ws + o);  o += (size_t)NSLOT * 4;
    float* slotw    = (float*)(ws + o); o += (size_t)NSLOT * 4;
    int*   counts   = (int*)(ws + o);
    int*   offsets  = counts + E_;     o += 256;
    unsigned short* Xg = (unsigned short*)(ws + o); o += (size_t)SPAD * C_ * 2;
    unsigned short* G  = (unsigned short*)(ws + o); o += (size_t)SPAD * H_ * 2;
    size_t need_slow = o;
    unsigned short* W1t = (unsigned short*)(ws + o); o += (size_t)E_ * H_ * C_ * 2;
    unsigned short* W3t = (unsigned short*)(ws + o); o += (size_t)E_ * H_ * C_ * 2;
    unsigned short* W2t = W1t;   // W1t region freed after gemm1
    size_t need_fast = o;

    hipMemsetAsync(d_out, 0, (size_t)out_size * sizeof(float), stream);
    if (ws_size < need_slow) return;

    router_kernel<<<N_TOK/4, 256, 0, stream>>>(x, Wg, sel, wts);
    assign_kernel<<<1, 256, 0, stream>>>(sel, wts, counts, offsets, pos, token_of, slotw);
    copy_kernel<<<NSLOT/4, 256, 0, stream>>>(x, pos, Xg);

    if (ws_size >= need_fast) {
        hipFuncSetAttribute((const void*)gemm1_ring, hipFuncAttributeMaxDynamicSharedMemorySize, 131072);
        hipFuncSetAttribute((const void*)gemm2_ring, hipFuncAttributeMaxDynamicSharedMemorySize, 98304);
        wconv_kernel<<<dim3(H_/64, C_/64, E_), 256, 0, stream>>>(W1, W1t, C_, H_);
        wconv_kernel<<<dim3(H_/64, C_/64, E_), 256, 0, stream>>>(W3, W3t, C_, H_);
        gemm1_ring<<<dim3(32, 256), 512, 131072, stream>>>(Xg, W1t, W3t, G, counts, offsets);
        wconv_kernel<<<dim3(C_/64, H_/64, E_), 256, 0, stream>>>(W2, W2t, H_, C_);
        gemm2_ring<<<dim3(8, 256), 512, 98304, stream>>>(G, W2t, out, counts, offsets, token_of, slotw);
    } else {
        gemm1_slow<<<dim3(H_/BN, E_*32), 256, 0, stream>>>(Xg, W1, W3, G, counts, offsets);
        gemm2_slow<<<dim3(C_/BN, E_*32), 256, 0, stream>>>(G, W2, out, counts, offsets, token_of, slotw);
    }
}

// Round 11
// 495.054 us; speedup vs baseline: 1.2007x; 1.1816x over previous
//
#include <hip/hip_runtime.h>
#include <hip/hip_bf16.h>

#define E_     8
#define C_     1024
#define H_     4096
#define N_TOK  4096
#define TOPK   2
#define NSLOT  (N_TOK*TOPK)   // 8192
#define SPAD   (NSLOT+256)    // padded rows for 256-row tile-tail reads

#define LPAD 40               // slow-path LDS row stride

typedef __attribute__((ext_vector_type(4))) float f32x4;
typedef __attribute__((ext_vector_type(8))) short short8;

__device__ __forceinline__ unsigned short f2bf(float f) {
    return __builtin_bit_cast(unsigned short, __float2bfloat16(f));
}

__device__ __forceinline__ void gload16(const void* g, const void* l) {
    __builtin_amdgcn_global_load_lds(
        (const __attribute__((address_space(1))) unsigned int*)g,
        (__attribute__((address_space(3))) unsigned int*)l, 16, 0, 0);
}

#define WAITVM_(n) asm volatile("s_waitcnt vmcnt(" #n ")" ::: "memory")
#define WAITVM(n) WAITVM_(n)

// ---------------- router: 1 wave per token (no atomics) ----------------
__global__ void router_kernel(const float* __restrict__ x, const float* __restrict__ Wg,
                              int* __restrict__ sel, float* __restrict__ wts) {
    int wave = (blockIdx.x * blockDim.x + threadIdx.x) >> 6;
    int lane = threadIdx.x & 63;
    if (wave >= N_TOK) return;
    const float* xr = x + (size_t)wave * C_;
    float acc[E_];
#pragma unroll
    for (int e = 0; e < E_; ++e) acc[e] = 0.f;
    for (int c = lane; c < C_; c += 64) {
        float xv = xr[c];
#pragma unroll
        for (int e = 0; e < E_; ++e) acc[e] += xv * Wg[e * C_ + c];
    }
#pragma unroll
    for (int e = 0; e < E_; ++e) {
#pragma unroll
        for (int off = 32; off > 0; off >>= 1) acc[e] += __shfl_xor(acc[e], off);
    }
    if (lane == 0) {
        float mx = acc[0];
#pragma unroll
        for (int e = 1; e < E_; ++e) mx = fmaxf(mx, acc[e]);
        float p[E_]; float s = 0.f;
#pragma unroll
        for (int e = 0; e < E_; ++e) { p[e] = __expf(acc[e] - mx); s += p[e]; }
        float inv = 1.f / s;
#pragma unroll
        for (int e = 0; e < E_; ++e) p[e] *= inv;
        int b0 = 0; float v0 = p[0];
#pragma unroll
        for (int e = 1; e < E_; ++e) if (p[e] > v0) { v0 = p[e]; b0 = e; }
        int b1 = -1; float v1 = -1.f;
#pragma unroll
        for (int e = 0; e < E_; ++e) { if (e != b0 && p[e] > v1) { v1 = p[e]; b1 = e; } }
        float isum = 1.f / (v0 + v1);
        sel[wave*2]   = b0; sel[wave*2+1] = b1;
        wts[wave*2]   = v0 * isum; wts[wave*2+1] = v1 * isum;
    }
}

// ---------------- assign: deterministic positions, single block ----------------
__global__ void assign_kernel(const int* __restrict__ sel, const float* __restrict__ wts,
                              int* __restrict__ counts, int* __restrict__ offsets,
                              int* __restrict__ pos_of_slot, int* __restrict__ token_of,
                              float* __restrict__ slotw) {
    __shared__ int cnt[256][E_];
    __shared__ int offs[E_];
    int t = threadIdx.x;
    const int PER = NSLOT / 256;   // 32
    int base = t * PER;
    int loc[E_];
#pragma unroll
    for (int e = 0; e < E_; ++e) loc[e] = 0;
    for (int i = 0; i < PER; ++i) loc[sel[base + i]]++;
#pragma unroll
    for (int e = 0; e < E_; ++e) cnt[t][e] = loc[e];
    __syncthreads();
    if (t < E_) {
        int run = 0;
        for (int i = 0; i < 256; ++i) { int c = cnt[i][t]; cnt[i][t] = run; run += c; }
        counts[t] = run;
    }
    __syncthreads();
    if (t == 0) {
        int s = 0;
        for (int e = 0; e < E_; ++e) { offs[e] = s; offsets[e] = s; s += counts[e]; }
    }
    __syncthreads();
    int run[E_];
#pragma unroll
    for (int e = 0; e < E_; ++e) run[e] = offs[e] + cnt[t][e];
    for (int i = 0; i < PER; ++i) {
        int s = base + i;
        int e = sel[s];
        int p = run[e]++;
        pos_of_slot[s] = p;
        token_of[p] = s >> 1;
        slotw[p] = wts[s];
    }
}

// ---------------- copy: gather token rows to bf16 ----------------
__global__ void copy_kernel(const float* __restrict__ x, const int* __restrict__ pos_of_slot,
                            unsigned short* __restrict__ Xg) {
    int slot = blockIdx.x * 4 + (threadIdx.x >> 6);
    int lane = threadIdx.x & 63;
    int pos = pos_of_slot[slot];
    int n = slot >> 1;
    const float* xr = x + (size_t)n * C_;
    unsigned short* dst = Xg + (size_t)pos * C_;
#pragma unroll
    for (int i = 0; i < 4; ++i) {
        int c0 = i * 256 + lane * 4;
        float4 v = *(const float4*)(xr + c0);
        ushort4 b;
        b.x = f2bf(v.x); b.y = f2bf(v.y); b.z = f2bf(v.z); b.w = f2bf(v.w);
        *(ushort4*)(dst + c0) = b;
    }
}

// ---------------- wconv: per-expert transpose fp32 [R][Cc] -> bf16 [Cc][R] ----------------
__global__ void wconv_kernel(const float* __restrict__ src, unsigned short* __restrict__ dst,
                             int R, int Cc) {
    int e = blockIdx.z;
    int c0 = blockIdx.x * 64;
    int r0 = blockIdx.y * 64;
    const float* s = src + (size_t)e * R * Cc;
    unsigned short* d = dst + (size_t)e * R * Cc;
    __shared__ unsigned short t_[64][72];
    int t = threadIdx.x;
    int tr = t >> 4, tc4 = (t & 15) * 4;
#pragma unroll
    for (int i = 0; i < 4; ++i) {
        int r = tr + i * 16;
        float4 v = *(const float4*)(s + (size_t)(r0 + r) * Cc + c0 + tc4);
        t_[r][tc4+0] = f2bf(v.x); t_[r][tc4+1] = f2bf(v.y);
        t_[r][tc4+2] = f2bf(v.z); t_[r][tc4+3] = f2bf(v.w);
    }
    __syncthreads();
    int oc = t >> 2, seg = (t & 3) * 16;
    short8 w0, w1;
#pragma unroll
    for (int j = 0; j < 8; ++j) {
        w0[j] = (short)t_[seg + j][oc];
        w1[j] = (short)t_[seg + 8 + j][oc];
    }
    unsigned short* dp = d + (size_t)(c0 + oc) * R + r0 + seg;
    *(short8*)dp = w0;
    *(short8*)(dp + 8) = w1;
}

// ============ gemm1: r4's proven 4-phase deep pipeline (189us, MfmaUtil 35%) ============
// 256x128 tile, BK=64, 8 waves, dbuf 128KB LDS, NO expert pinning (r9 showed pinning
// raises gemm1 fetch 165->295MB). Chunk swizzle phys = logical ^ (row&7) both-sides.

#define G1_BM 256
#define G1_BN 128
#define G1_BK 64
#define G1_NT (C_/G1_BK)   // 16

#define G1_PHASE(F, ACCX, WN)                                                       \
  {                                                                                 \
    __builtin_amdgcn_s_barrier();                                                   \
    {                                                                               \
      int pn = (t + 1) & 1;                                                         \
      int tsrc = (t + 1 < G1_NT) ? (t + 1) : t;                                     \
      int k0n = tsrc * G1_BK;                                                       \
      if ((F) == 0 || (F) == 1) {                                                   \
        _Pragma("unroll")                                                           \
        for (int r = 0; r < 2; ++r) {                                               \
          int row = (F)*128 + r*64 + srow;                                          \
          int lch = pch ^ (row & 7);                                                \
          gload16(Ap + (size_t)row * C_ + k0n + lch*8,                              \
                  (char*)As + pn*32768 + (((F)*128 + r*64 + wid*8) << 7));          \
        }                                                                           \
      } else {                                                                      \
        const unsigned short* gsrc = ((F) == 2) ? B1p : B3p;                        \
        char* ldst = (char*)(((F) == 2) ? B1s : B3s) + pn*16384;                    \
        _Pragma("unroll")                                                           \
        for (int r = 0; r < 2; ++r) {                                               \
          int row = r*64 + srow;                                                    \
          int lch = pch ^ (row & 7);                                                \
          gload16(gsrc + (size_t)row * C_ + k0n + lch*8,                            \
                  ldst + ((r*64 + wid*8) << 7));                                    \
        }                                                                           \
      }                                                                             \
    }                                                                               \
    WAITVM(WN);                                                                     \
    __builtin_amdgcn_s_barrier();                                                   \
    __builtin_amdgcn_sched_barrier(0);                                              \
    {                                                                               \
      int p = t & 1; int ks = (F) & 1;                                              \
      const unsigned short* Ab = As + p*16384;                                      \
      const unsigned short* Bb = (((F) < 2) ? B1s : B3s) + p*8192;                  \
      short8 a[4], b[4];                                                            \
      _Pragma("unroll")                                                             \
      for (int m = 0; m < 4; ++m) {                                                 \
        int row = wm*64 + m*16 + fr;                                                \
        a[m] = *(const short8*)(Ab + row*64 + (((ks*4 + q) ^ (row & 7)) << 3));     \
      }                                                                             \
      _Pragma("unroll")                                                             \
      for (int n = 0; n < 4; ++n) {                                                 \
        int row = wn*64 + n*16 + fr;                                                \
        b[n] = *(const short8*)(Bb + row*64 + (((ks*4 + q) ^ (row & 7)) << 3));     \
      }                                                                             \
      __builtin_amdgcn_s_setprio(1);                                                \
      _Pragma("unroll")                                                             \
      for (int m = 0; m < 4; ++m)                                                   \
        _Pragma("unroll")                                                           \
        for (int n = 0; n < 4; ++n)                                                 \
          ACCX[m][n] = __builtin_amdgcn_mfma_f32_16x16x32_bf16(a[m], b[n], ACCX[m][n], 0, 0, 0); \
      __builtin_amdgcn_s_setprio(0);                                                \
    }                                                                               \
  }

__global__ __launch_bounds__(512, 2) void gemm1_f8(
        const unsigned short* __restrict__ Xg, const unsigned short* __restrict__ W1t,
        const unsigned short* __restrict__ W3t, unsigned short* __restrict__ G,
        const int* __restrict__ counts, const int* __restrict__ offsets) {
    int ct = blockIdx.x;            // H/128 = 32
    int rslot = blockIdx.y;         // e*32 + rt
    int e = rslot >> 5, rt = rslot & 31;
    int ne = counts[e];
    if (rt * G1_BM >= ne) return;
    int row0 = offsets[e] + rt * G1_BM;
    int n0 = ct * G1_BN;

    extern __shared__ unsigned short lds[];
    unsigned short* As  = lds;                 // [2][256*64]  64KB
    unsigned short* B1s = lds + 2*256*64;      // [2][128*64]  32KB
    unsigned short* B3s = B1s + 2*128*64;      // [2][128*64]  32KB

    int tid = threadIdx.x, lane = tid & 63, wid = tid >> 6;
    int wm = wid >> 1, wn = wid & 1;
    int fr = lane & 15, q = lane >> 4;
    int srow = wid * 8 + (lane >> 3);
    int pch  = lane & 7;

    const unsigned short* Ap  = Xg + (size_t)row0 * C_;
    const unsigned short* B1p = W1t + ((size_t)e * H_ + n0) * C_;
    const unsigned short* B3p = W3t + ((size_t)e * H_ + n0) * C_;

    f32x4 acc1[4][4], acc3[4][4];
#pragma unroll
    for (int m = 0; m < 4; ++m)
#pragma unroll
        for (int n = 0; n < 4; ++n) {
            acc1[m][n] = (f32x4){0.f,0.f,0.f,0.f};
            acc3[m][n] = (f32x4){0.f,0.f,0.f,0.f};
        }

    // prologue: stage K-tile 0 (order: A0, A1, B1, B3) into buffer 0
#pragma unroll
    for (int u = 0; u < 2; ++u)
#pragma unroll
        for (int r = 0; r < 2; ++r) {
            int row = u*128 + r*64 + srow;
            int lch = pch ^ (row & 7);
            gload16(Ap + (size_t)row * C_ + lch*8,
                    (char*)As + ((u*128 + r*64 + wid*8) << 7));
        }
#pragma unroll
    for (int r = 0; r < 2; ++r) {
        int row = r*64 + srow;
        int lch = pch ^ (row & 7);
        gload16(B1p + (size_t)row * C_ + lch*8, (char*)B1s + ((r*64 + wid*8) << 7));
    }
#pragma unroll
    for (int r = 0; r < 2; ++r) {
        int row = r*64 + srow;
        int lch = pch ^ (row & 7);
        gload16(B3p + (size_t)row * C_ + lch*8, (char*)B3s + ((r*64 + wid*8) << 7));
    }

    for (int t = 0; t < G1_NT; ++t) {
        G1_PHASE(0, acc1, 4)
        G1_PHASE(1, acc1, 6)
        G1_PHASE(2, acc3, 6)
        G1_PHASE(3, acc3, 8)
    }
    WAITVM(0);   // drain dummy last-tile staging before kernel end

    int cfr = lane & 15;
#pragma unroll
    for (int m = 0; m < 4; ++m)
#pragma unroll
        for (int rg = 0; rg < 4; ++rg) {
            int row = wm*64 + m*16 + q*4 + rg;
            if (rt * G1_BM + row < ne) {
                size_t gbase = (size_t)(row0 + row) * H_ + n0 + wn*64;
#pragma unroll
                for (int n = 0; n < 4; ++n) {
                    float h1 = acc1[m][n][rg];
                    float h3 = acc3[m][n][rg];
                    float g = h1 * h3 / (1.f + __expf(-h1));
                    G[gbase + n*16 + cfr] = f2bf(g);
                }
            }
        }
}

// ============ gemm2: K-split x2, 3-buf BK=32 ring, 72KB LDS -> 2 blocks/CU ============
// 4096 blocks (e8 x ksp2 x ct8 x rt32 -- rt MUST cover 32 tiles: expert counts exceed
// 1024 rows; r10's rt<4 dropped tail rows, absmax 0.93). Expert-pinned XCD swizzle
// (e=b&7; fetch cut 4x, r7). Two INDEPENDENT resident blocks per CU overlap each other's
// barrier/LDS/MFMA windows (the m114 TLP mechanism gemm2 lacked at 1 block/CU).
// LDS: transposed 1024B blocks (16 rows x 4 chunks, chunk-major), staged per-lane,
// conflict-free ds_read_b128 (r6: 0 conflicts).
// Ring: {WAITVM(3); barrier; STAGE(t+2 -> buf (t+2)%3); reads(buf t%3); MFMA}. WAR safe:
// stage after barrier overwrites buf(t-1) whose reads all precede the barrier (per-wave
// lgkmcnt before MFMA consumes ds_read results; per-wave WAITVM precedes barrier so all
// waves' tile-t loads are retired once any wave crosses). K-halves combine via the
// atomicAdd epilogue (out pre-zeroed).

#define G2_KT (H_/2)      // 2048 per K-split
#define G2_NT (G2_KT/32)  // 64 K-tiles

__global__ __launch_bounds__(512, 4) void gemm2_ks(
        const unsigned short* __restrict__ G, const unsigned short* __restrict__ W2t,
        float* __restrict__ out, const int* __restrict__ counts,
        const int* __restrict__ offsets, const int* __restrict__ token_of,
        const float* __restrict__ slotw) {
    int b = blockIdx.x;             // [0, 4096)
    int e = b & 7;
    int j = b >> 3;                 // [0, 512)
    int ksp = j & 1;
    int ct = (j >> 1) & 7;          // 8 col tiles over C
    int rt = j >> 4;                // [0, 32)
    int ne = counts[e];
    if (rt * 256 >= ne) return;
    int row0 = offsets[e] + rt * 256;
    int n0 = ct * 128;
    int kbase = ksp * G2_KT;

    extern __shared__ char lds2[];
    char* As = lds2;             // 3 bufs x 16384 B (16 blocks of 1024B)
    char* Bs = lds2 + 49152;     // 3 bufs x 8192 B  (total 72KB)

    int tid = threadIdx.x, lane = tid & 63, wid = tid >> 6;   // 8 waves (4M x 2N)
    int wm = wid >> 1, wn = wid & 1;
    int fr = lane & 15, q = lane >> 4;
    int arow = lane & 15, akch = lane >> 4;

    const unsigned short* Ap = G + (size_t)row0 * H_ + kbase;
    const unsigned short* Bp = W2t + ((size_t)e * C_ + n0) * H_ + kbase;

    f32x4 acc[4][4];
#pragma unroll
    for (int m = 0; m < 4; ++m)
#pragma unroll
        for (int n = 0; n < 4; ++n) acc[m][n] = (f32x4){0.f,0.f,0.f,0.f};

    auto STAGE = [&](int ts, int buf) {   // 3 loads/wave/tile
        int k0 = ts * 32;
#pragma unroll
        for (int jj = 0; jj < 2; ++jj) {
            int ab = wid * 2 + jj;         // A block 0..15
            gload16(Ap + (size_t)(ab * 16 + arow) * H_ + k0 + akch * 8,
                    As + buf * 16384 + ab * 1024);
        }
        gload16(Bp + (size_t)(wid * 16 + arow) * H_ + k0 + akch * 8,
                Bs + buf * 8192 + wid * 1024);
    };

    STAGE(0, 0); STAGE(1, 1);       // 6 loads in flight
    for (int t = 0; t < G2_NT; ++t) {
        WAITVM(3);                  // retire tile t's loads (leave tile t+1's 3)
        __builtin_amdgcn_s_barrier();
        __builtin_amdgcn_sched_barrier(0);
        int ts = (t + 2 < G2_NT) ? t + 2 : G2_NT - 1;   // tail: dummy re-stage
        STAGE(ts, (t + 2) % 3);
        int buf = t % 3;
        short8 a[4], bb[4];
#pragma unroll
        for (int m = 0; m < 4; ++m)
            a[m] = *(const short8*)(As + buf * 16384 + (wm * 4 + m) * 1024 + q * 256 + fr * 16);
#pragma unroll
        for (int n = 0; n < 4; ++n)
            bb[n] = *(const short8*)(Bs + buf * 8192 + (wn * 4 + n) * 1024 + q * 256 + fr * 16);
        __builtin_amdgcn_s_setprio(1);
#pragma unroll
        for (int m = 0; m < 4; ++m)
#pragma unroll
            for (int n = 0; n < 4; ++n)
                acc[m][n] = __builtin_amdgcn_mfma_f32_16x16x32_bf16(a[m], bb[n], acc[m][n], 0, 0, 0);
        __builtin_amdgcn_s_setprio(0);
    }
    WAITVM(0);   // drain dummy staging before kernel end

    // epilogue: scatter-add weighted K-half partial into out
#pragma unroll
    for (int m = 0; m < 4; ++m)
#pragma unroll
        for (int rg = 0; rg < 4; ++rg) {
            int row = wm*64 + m*16 + q*4 + rg;
            if (rt * 256 + row < ne) {
                int grow = row0 + row;
                int tok = token_of[grow];
                float w = slotw[grow];
                float* orow = out + (size_t)tok * C_ + n0 + wn*64;
#pragma unroll
                for (int n = 0; n < 4; ++n)
                    atomicAdd(orow + n*16 + fr, acc[m][n][rg] * w);
            }
        }
}

// ============ SLOW PATH (fallback if ws too small) ============
#define BM 128
#define BN 128
#define BK 32
__global__ __launch_bounds__(256, 2) void gemm1_slow(
        const unsigned short* __restrict__ Xg, const float* __restrict__ W1,
        const float* __restrict__ W3, unsigned short* __restrict__ G,
        const int* __restrict__ counts, const int* __restrict__ offsets) {
    int ct = blockIdx.x;
    int rslot = blockIdx.y;
    int e = rslot >> 5, rt = rslot & 31;
    int ne = counts[e];
    if (rt * BM >= ne) return;
    int row0 = offsets[e] + rt * BM;
    int n0 = ct * BN;

    __shared__ unsigned short As[BM][LPAD];
    __shared__ unsigned short B1s[BN][LPAD];
    __shared__ unsigned short B3s[BN][LPAD];

    int tid = threadIdx.x;
    int lane = tid & 63, wid = tid >> 6;
    int wr = (wid >> 1) * 64, wc = (wid & 1) * 64;

    f32x4 acc1[4][4], acc3[4][4];
#pragma unroll
    for (int m = 0; m < 4; ++m)
#pragma unroll
        for (int n = 0; n < 4; ++n) {
            acc1[m][n] = (f32x4){0.f,0.f,0.f,0.f};
            acc3[m][n] = (f32x4){0.f,0.f,0.f,0.f};
        }

    const float* B1p = W1 + (size_t)e * C_ * H_ + n0;
    const float* B3p = W3 + (size_t)e * C_ * H_ + n0;
    int chunk = tid & 3, rr = tid >> 2;
    int kq = tid >> 5, n4 = tid & 31;

    for (int k0 = 0; k0 < C_; k0 += BK) {
        __syncthreads();
#pragma unroll
        for (int h = 0; h < 2; ++h) {
            int row = rr + h * 64;
            uint4 v = *(const uint4*)(Xg + (size_t)(row0 + row) * C_ + k0 + chunk * 8);
            *(uint4*)&As[row][chunk * 8] = v;
        }
        {
            float4 r0 = *(const float4*)(B1p + (size_t)(k0 + kq*4 + 0) * H_ + n4*4);
            float4 r1 = *(const float4*)(B1p + (size_t)(k0 + kq*4 + 1) * H_ + n4*4);
            float4 r2 = *(const float4*)(B1p + (size_t)(k0 + kq*4 + 2) * H_ + n4*4);
            float4 r3 = *(const float4*)(B1p + (size_t)(k0 + kq*4 + 3) * H_ + n4*4);
            ushort4 w0 = {f2bf(r0.x), f2bf(r1.x), f2bf(r2.x), f2bf(r3.x)};
            ushort4 w1 = {f2bf(r0.y), f2bf(r1.y), f2bf(r2.y), f2bf(r3.y)};
            ushort4 w2 = {f2bf(r0.z), f2bf(r1.z), f2bf(r2.z), f2bf(r3.z)};
            ushort4 w3 = {f2bf(r0.w), f2bf(r1.w), f2bf(r2.w), f2bf(r3.w)};
            *(ushort4*)&B1s[n4*4+0][kq*4] = w0;
            *(ushort4*)&B1s[n4*4+1][kq*4] = w1;
            *(ushort4*)&B1s[n4*4+2][kq*4] = w2;
            *(ushort4*)&B1s[n4*4+3][kq*4] = w3;
            r0 = *(const float4*)(B3p + (size_t)(k0 + kq*4 + 0) * H_ + n4*4);
            r1 = *(const float4*)(B3p + (size_t)(k0 + kq*4 + 1) * H_ + n4*4);
            r2 = *(const float4*)(B3p + (size_t)(k0 + kq*4 + 2) * H_ + n4*4);
            r3 = *(const float4*)(B3p + (size_t)(k0 + kq*4 + 3) * H_ + n4*4);
            w0 = (ushort4){f2bf(r0.x), f2bf(r1.x), f2bf(r2.x), f2bf(r3.x)};
            w1 = (ushort4){f2bf(r0.y), f2bf(r1.y), f2bf(r2.y), f2bf(r3.y)};
            w2 = (ushort4){f2bf(r0.z), f2bf(r1.z), f2bf(r2.z), f2bf(r3.z)};
            w3 = (ushort4){f2bf(r0.w), f2bf(r1.w), f2bf(r2.w), f2bf(r3.w)};
            *(ushort4*)&B3s[n4*4+0][kq*4] = w0;
            *(ushort4*)&B3s[n4*4+1][kq*4] = w1;
            *(ushort4*)&B3s[n4*4+2][kq*4] = w2;
            *(ushort4*)&B3s[n4*4+3][kq*4] = w3;
        }
        __syncthreads();
        int q = lane >> 4, fr = lane & 15;
        short8 a[4], b1[4], b3[4];
#pragma unroll
        for (int m = 0; m < 4; ++m) a[m] = *(const short8*)&As[wr + m*16 + fr][q*8];
#pragma unroll
        for (int n = 0; n < 4; ++n) {
            b1[n] = *(const short8*)&B1s[wc + n*16 + fr][q*8];
            b3[n] = *(const short8*)&B3s[wc + n*16 + fr][q*8];
        }
#pragma unroll
        for (int m = 0; m < 4; ++m)
#pragma unroll
            for (int n = 0; n < 4; ++n) {
                acc1[m][n] = __builtin_amdgcn_mfma_f32_16x16x32_bf16(a[m], b1[n], acc1[m][n], 0, 0, 0);
                acc3[m][n] = __builtin_amdgcn_mfma_f32_16x16x32_bf16(a[m], b3[n], acc3[m][n], 0, 0, 0);
            }
    }
    int q = lane >> 4, cfr = lane & 15;
#pragma unroll
    for (int m = 0; m < 4; ++m) {
#pragma unroll
        for (int rg = 0; rg < 4; ++rg) {
            int row = wr + m*16 + q*4 + rg;
            if (rt * BM + row < ne) {
                size_t gbase = (size_t)(row0 + row) * H_ + n0;
#pragma unroll
                for (int n = 0; n < 4; ++n) {
                    float h1 = acc1[m][n][rg];
                    float h3 = acc3[m][n][rg];
                    float g = h1 * h3 / (1.f + __expf(-h1));
                    G[gbase + wc + n*16 + cfr] = f2bf(g);
                }
            }
        }
    }
}

__global__ __launch_bounds__(256, 2) void gemm2_slow(
        const unsigned short* __restrict__ G, const float* __restrict__ W2,
        float* __restrict__ out, const int* __restrict__ counts,
        const int* __restrict__ offsets, const int* __restrict__ token_of,
        const float* __restrict__ slotw) {
    int ct = blockIdx.x;
    int rslot = blockIdx.y;
    int e = rslot >> 5, rt = rslot & 31;
    int ne = counts[e];
    if (rt * BM >= ne) return;
    int row0 = offsets[e] + rt * BM;
    int n0 = ct * BN;

    __shared__ unsigned short As[BM][LPAD];
    __shared__ unsigned short Bs[BN][LPAD];

    int tid = threadIdx.x;
    int lane = tid & 63, wid = tid >> 6;
    int wr = (wid >> 1) * 64, wc = (wid & 1) * 64;

    f32x4 acc[4][4];
#pragma unroll
    for (int m = 0; m < 4; ++m)
#pragma unroll
        for (int n = 0; n < 4; ++n) acc[m][n] = (f32x4){0.f,0.f,0.f,0.f};

    const float* Bp = W2 + (size_t)e * H_ * C_ + n0;
    int chunk = tid & 3, rr = tid >> 2;
    int kq = tid >> 5, n4 = tid & 31;

    for (int k0 = 0; k0 < H_; k0 += BK) {
        __syncthreads();
#pragma unroll
        for (int h = 0; h < 2; ++h) {
            int row = rr + h * 64;
            uint4 v = *(const uint4*)(G + (size_t)(row0 + row) * H_ + k0 + chunk * 8);
            *(uint4*)&As[row][chunk * 8] = v;
        }
        {
            float4 r0 = *(const float4*)(Bp + (size_t)(k0 + kq*4 + 0) * C_ + n4*4);
            float4 r1 = *(const float4*)(Bp + (size_t)(k0 + kq*4 + 1) * C_ + n4*4);
            float4 r2 = *(const float4*)(Bp + (size_t)(k0 + kq*4 + 2) * C_ + n4*4);
            float4 r3 = *(const float4*)(Bp + (size_t)(k0 + kq*4 + 3) * C_ + n4*4);
            ushort4 w0 = {f2bf(r0.x), f2bf(r1.x), f2bf(r2.x), f2bf(r3.x)};
            ushort4 w1 = {f2bf(r0.y), f2bf(r1.y), f2bf(r2.y), f2bf(r3.y)};
            ushort4 w2 = {f2bf(r0.z), f2bf(r1.z), f2bf(r2.z), f2bf(r3.z)};
            ushort4 w3 = {f2bf(r0.w), f2bf(r1.w), f2bf(r2.w), f2bf(r3.w)};
            *(ushort4*)&Bs[n4*4+0][kq*4] = w0;
            *(ushort4*)&Bs[n4*4+1][kq*4] = w1;
            *(ushort4*)&Bs[n4*4+2][kq*4] = w2;
            *(ushort4*)&Bs[n4*4+3][kq*4] = w3;
        }
        __syncthreads();
        int q = lane >> 4, fr = lane & 15;
        short8 a[4], b[4];
#pragma unroll
        for (int m = 0; m < 4; ++m) a[m] = *(const short8*)&As[wr + m*16 + fr][q*8];
#pragma unroll
        for (int n = 0; n < 4; ++n) b[n] = *(const short8*)&Bs[wc + n*16 + fr][q*8];
#pragma unroll
        for (int m = 0; m < 4; ++m)
#pragma unroll
            for (int n = 0; n < 4; ++n)
                acc[m][n] = __builtin_amdgcn_mfma_f32_16x16x32_bf16(a[m], b[n], acc[m][n], 0, 0, 0);
    }
    int q = lane >> 4, cfr = lane & 15;
#pragma unroll
    for (int m = 0; m < 4; ++m) {
#pragma unroll
        for (int rg = 0; rg < 4; ++rg) {
            int row = wr + m*16 + q*4 + rg;
            if (rt * BM + row < ne) {
                int grow = row0 + row;
                int tok = token_of[grow];
                float w = slotw[grow];
                float* orow = out + (size_t)tok * C_ + n0;
#pragma unroll
                for (int n = 0; n < 4; ++n)
                    atomicAdd(orow + wc + n*16 + cfr, acc[m][n][rg] * w);
            }
        }
    }
}

extern "C" void kernel_launch(void* const* d_in, const int* in_sizes, int n_in,
                              void* d_out, int out_size, void* d_ws, size_t ws_size,
                              hipStream_t stream) {
    const float* x  = (const float*)d_in[0];
    const float* Wg = (const float*)d_in[1];
    const float* W1 = (const float*)d_in[2];
    const float* W2 = (const float*)d_in[3];
    const float* W3 = (const float*)d_in[4];
    float* out = (float*)d_out;

    char* ws = (char*)d_ws;
    size_t o = 0;
    int*   sel      = (int*)(ws + o);  o += (size_t)NSLOT * 4;
    float* wts      = (float*)(ws + o); o += (size_t)NSLOT * 4;
    int*   pos      = (int*)(ws + o);  o += (size_t)NSLOT * 4;
    int*   token_of = (int*)(ws + o);  o += (size_t)NSLOT * 4;
    float* slotw    = (float*)(ws + o); o += (size_t)NSLOT * 4;
    int*   counts   = (int*)(ws + o);
    int*   offsets  = counts + E_;     o += 256;
    unsigned short* Xg = (unsigned short*)(ws + o); o += (size_t)SPAD * C_ * 2;
    unsigned short* G  = (unsigned short*)(ws + o); o += (size_t)SPAD * H_ * 2;
    size_t need_slow = o;
    unsigned short* W1t = (unsigned short*)(ws + o); o += (size_t)E_ * H_ * C_ * 2;
    unsigned short* W3t = (unsigned short*)(ws + o); o += (size_t)E_ * H_ * C_ * 2;
    unsigned short* W2t = W1t;   // W1t region freed after gemm1
    size_t need_fast = o;

    hipMemsetAsync(d_out, 0, (size_t)out_size * sizeof(float), stream);
    if (ws_size < need_slow) return;

    router_kernel<<<N_TOK/4, 256, 0, stream>>>(x, Wg, sel, wts);
    assign_kernel<<<1, 256, 0, stream>>>(sel, wts, counts, offsets, pos, token_of, slotw);
    copy_kernel<<<NSLOT/4, 256, 0, stream>>>(x, pos, Xg);

    if (ws_size >= need_fast) {
        hipFuncSetAttribute((const void*)gemm1_f8, hipFuncAttributeMaxDynamicSharedMemorySize, 131072);
        hipFuncSetAttribute((const void*)gemm2_ks, hipFuncAttributeMaxDynamicSharedMemorySize, 73728);
        wconv_kernel<<<dim3(H_/64, C_/64, E_), 256, 0, stream>>>(W1, W1t, C_, H_);
        wconv_kernel<<<dim3(H_/64, C_/64, E_), 256, 0, stream>>>(W3, W3t, C_, H_);
        gemm1_f8<<<dim3(H_/G1_BN, E_*32), 512, 131072, stream>>>(Xg, W1t, W3t, G, counts, offsets);
        wconv_kernel<<<dim3(C_/64, H_/64, E_), 256, 0, stream>>>(W2, W2t, H_, C_);
        gemm2_ks<<<4096, 512, 73728, stream>>>(G, W2t, out, counts, offsets, token_of, slotw);
    } else {
        gemm1_slow<<<dim3(H_/BN, E_*32), 256, 0, stream>>>(Xg, W1, W3, G, counts, offsets);
        gemm2_slow<<<dim3(C_/BN, E_*32), 256, 0, stream>>>(G, W2, out, counts, offsets, token_of, slotw);
    }
}